// Round 1
// baseline (464.464 us; speedup 1.0000x reference)
//
#include <hip/hip_runtime.h>
#include <stdint.h>

#define H_ 1024
#define NH_ 16
#define HD_ 64
#define B_ 4
#define S_ 2048
#define M_ (B_*S_)

typedef unsigned short u16;
typedef __attribute__((ext_vector_type(8))) short bf16x8;
typedef __attribute__((ext_vector_type(4))) float f32x4;
typedef __attribute__((ext_vector_type(4))) unsigned int u32x4;

__device__ __forceinline__ u16 f2bf(float f) {
  union { float f; uint32_t u; } v; v.f = f;
  uint32_t u = v.u + 0x7FFFu + ((v.u >> 16) & 1u);
  return (u16)(u >> 16);
}

static __device__ __forceinline__ f32x4 mfma16(bf16x8 a, bf16x8 b, f32x4 c) {
  return __builtin_amdgcn_mfma_f32_16x16x32_bf16(a, b, c, 0, 0, 0);
}

// ---------------- conversion kernels ----------------

__global__ __launch_bounds__(256) void cvt_hs_kernel(const float* __restrict__ in, u16* __restrict__ out) {
  int i = blockIdx.x * 256 + threadIdx.x;   // each thread: 8 elems
  const f32x4* p = (const f32x4*)in;
  f32x4 a = p[2*i], b = p[2*i+1];
  u32x4 o;
  o.x = (uint32_t)f2bf(a.x) | ((uint32_t)f2bf(a.y) << 16);
  o.y = (uint32_t)f2bf(a.z) | ((uint32_t)f2bf(a.w) << 16);
  o.z = (uint32_t)f2bf(b.x) | ((uint32_t)f2bf(b.y) << 16);
  o.w = (uint32_t)f2bf(b.z) | ((uint32_t)f2bf(b.w) << 16);
  ((u32x4*)out)[i] = o;
}

// W (K x N) fp32 -> WT (N x K) bf16, for p in {q,k,v,o}
__global__ __launch_bounds__(256) void cvt_wT_kernel(const float* __restrict__ Wq, const float* __restrict__ Wk,
                                                     const float* __restrict__ Wv, const float* __restrict__ Wo,
                                                     u16* __restrict__ wt) {
  const int p = blockIdx.z;
  const float* W = (p == 0) ? Wq : (p == 1) ? Wk : (p == 2) ? Wv : Wo;
  __shared__ float tile[64][65];
  const int tr = blockIdx.y, tc = blockIdx.x, t = threadIdx.x;
#pragma unroll
  for (int it = 0; it < 16; ++it) {
    int idx = it * 256 + t, r = idx >> 6, c = idx & 63;
    tile[r][c] = W[(size_t)(tr*64 + r) * H_ + tc*64 + c];
  }
  __syncthreads();
  u16* outp = wt + (size_t)p * H_ * H_;
#pragma unroll
  for (int it = 0; it < 16; ++it) {
    int idx = it * 256 + t, r = idx >> 6, c = idx & 63;
    outp[(size_t)(tc*64 + r) * H_ + tr*64 + c] = f2bf(tile[c][r]);
  }
}

// ---------------- GEMM main loop (C = A(MxK) * Bt(NxK)^T), K=1024 ----------------
// 128x128 tile, BK=32, 4 waves (2x2), each wave 4x4 fragments of 16x16x32 MFMA.
// LDS rows padded to 40 shorts (80B, 16B-aligned, 2-way-max bank conflicts).

#define BKP 40

__device__ __forceinline__ void gemm_tile(const u16* __restrict__ A, const u16* __restrict__ Bt,
                                          int m0, int n0, u16* As, u16* Bs, f32x4 acc[4][4]) {
  const int tid = threadIdx.x;
  const int lane = tid & 63, wave = tid >> 6;
  const int wr = wave >> 1, wc = wave & 1;
  const int l15 = lane & 15, l4 = lane >> 4;
  const int sr = tid >> 2, sc = (tid & 3) * 8;
  const u16* Ap = A + (size_t)(m0 + sr) * H_ + sc;
  const u16* Bp = Bt + (size_t)(n0 + sr) * H_ + sc;
  for (int k0 = 0; k0 < H_; k0 += 32) {
    u32x4 a0 = *(const u32x4*)(Ap + k0);
    u32x4 a1 = *(const u32x4*)(Ap + (size_t)64 * H_ + k0);
    u32x4 b0 = *(const u32x4*)(Bp + k0);
    u32x4 b1 = *(const u32x4*)(Bp + (size_t)64 * H_ + k0);
    __syncthreads();
    *(u32x4*)&As[sr * BKP + sc] = a0;
    *(u32x4*)&As[(sr + 64) * BKP + sc] = a1;
    *(u32x4*)&Bs[sr * BKP + sc] = b0;
    *(u32x4*)&Bs[(sr + 64) * BKP + sc] = b1;
    __syncthreads();
    bf16x8 afr[4], bfr[4];
#pragma unroll
    for (int m = 0; m < 4; ++m) afr[m] = *(const bf16x8*)&As[(wr*64 + m*16 + l15) * BKP + l4*8];
#pragma unroll
    for (int n = 0; n < 4; ++n) bfr[n] = *(const bf16x8*)&Bs[(wc*64 + n*16 + l15) * BKP + l4*8];
#pragma unroll
    for (int m = 0; m < 4; ++m)
#pragma unroll
      for (int n = 0; n < 4; ++n)
        acc[m][n] = mfma16(afr[m], bfr[n], acc[m][n]);
  }
}

// QKV: C (8192 x 3072), epilogue scatters to qkv16[p][b][h][s][d] bf16 (+bias)
__global__ __launch_bounds__(256) void gemm_qkv_kernel(const u16* __restrict__ hs16, const u16* __restrict__ wt,
                                                       const float* __restrict__ bq, const float* __restrict__ bk,
                                                       const float* __restrict__ bv, u16* __restrict__ qkv16) {
  __shared__ __align__(16) u16 As[128*BKP], Bs[128*BKP];
  f32x4 acc[4][4] = {};
  const int m0 = blockIdx.y * 128, n0 = blockIdx.x * 128;
  gemm_tile(hs16, wt, m0, n0, As, Bs, acc);
  const int tid = threadIdx.x, lane = tid & 63, wave = tid >> 6;
  const int wr = wave >> 1, wc = wave & 1, l15 = lane & 15, l4 = lane >> 4;
  const int p = n0 >> 10;
  const float* bias = (p == 0) ? bq : (p == 1) ? bk : bv;
  u16* base = qkv16 + (size_t)p * ((size_t)B_*NH_*S_*HD_);
#pragma unroll
  for (int n = 0; n < 4; ++n) {
    int ncol = (n0 & 1023) + wc*64 + n*16 + l15;
    int h = ncol >> 6, d = ncol & 63;
    float bsv = bias[ncol];
#pragma unroll
    for (int m = 0; m < 4; ++m) {
#pragma unroll
      for (int r = 0; r < 4; ++r) {
        int row = m0 + wr*64 + m*16 + l4*4 + r;
        int b = row >> 11, s = row & 2047;
        base[(((size_t)b*NH_ + h)*S_ + s)*HD_ + d] = f2bf(acc[m][n][r] + bsv);
      }
    }
  }
}

// out-proj: C = ctx16 @ Wo + bo + residual(hs) -> fp32 xout
__global__ __launch_bounds__(256) void gemm_out_kernel(const u16* __restrict__ ctx16, const u16* __restrict__ wo,
                                                       const float* __restrict__ bo, const float* __restrict__ hs,
                                                       float* __restrict__ xout) {
  __shared__ __align__(16) u16 As[128*BKP], Bs[128*BKP];
  f32x4 acc[4][4] = {};
  const int m0 = blockIdx.y * 128, n0 = blockIdx.x * 128;
  gemm_tile(ctx16, wo, m0, n0, As, Bs, acc);
  const int tid = threadIdx.x, lane = tid & 63, wave = tid >> 6;
  const int wr = wave >> 1, wc = wave & 1, l15 = lane & 15, l4 = lane >> 4;
#pragma unroll
  for (int n = 0; n < 4; ++n) {
    int col = n0 + wc*64 + n*16 + l15;
    float bsv = bo[col];
#pragma unroll
    for (int m = 0; m < 4; ++m) {
#pragma unroll
      for (int r = 0; r < 4; ++r) {
        int row = m0 + wr*64 + m*16 + l4*4 + r;
        size_t off = (size_t)row * H_ + col;
        xout[off] = acc[m][n][r] + bsv + hs[off];
      }
    }
  }
}

// ---------------- flash attention ----------------
// block = (q-tile of 64 rows, head, batch); 4 waves, each wave owns 16 q-rows.
// KV tiles of 64; K staged row-major, V staged transposed (Vs[d][kv]); padded rows.

#define KP 72

__global__ __launch_bounds__(256) void attn_kernel(const u16* __restrict__ qkv16, const float* __restrict__ mask,
                                                   u16* __restrict__ ctx16) {
  __shared__ __align__(16) u16 Ks[64*KP], Vs[64*KP], Ps[4*16*KP];
  const int qb = blockIdx.x, h = blockIdx.y, b = blockIdx.z;
  const int tid = threadIdx.x, lane = tid & 63, wave = tid >> 6;
  const int l15 = lane & 15, l4 = lane >> 4;
  const size_t headoff = ((size_t)b * NH_ + h) * ((size_t)S_ * HD_);
  const size_t psz = (size_t)B_ * NH_ * S_ * HD_;
  const u16* Q = qkv16 + headoff;
  const u16* K = qkv16 + psz + headoff;
  const u16* V = qkv16 + 2*psz + headoff;
  const int q0 = qb * 64;
  bf16x8 aq[2];
#pragma unroll
  for (int t = 0; t < 2; ++t)
    aq[t] = *(const bf16x8*)(Q + (size_t)(q0 + wave*16 + l15) * HD_ + t*32 + l4*8);
  f32x4 O[4] = {};
  float mrun[4], lrun[4];
#pragma unroll
  for (int r = 0; r < 4; ++r) { mrun[r] = -1e30f; lrun[r] = 0.f; }
  const int strow = tid >> 3, stcol = (tid & 7) * 8;
  u16* Pw = &Ps[wave * 16 * KP];
  for (int kt = 0; kt < S_/64; ++kt) {
    const u16* Kt = K + (size_t)kt * 64 * HD_;
    const u16* Vt = V + (size_t)kt * 64 * HD_;
    __syncthreads();   // protect Ks/Vs from overwrite while prev iter still reading
#pragma unroll
    for (int j = 0; j < 2; ++j) {
      int row = j*32 + strow;
      *(u32x4*)&Ks[row * KP + stcol] = *(const u32x4*)(Kt + (size_t)row * HD_ + stcol);
      u32x4 vv = *(const u32x4*)(Vt + (size_t)row * HD_ + stcol);
      const u16* pv = (const u16*)&vv;
#pragma unroll
      for (int i = 0; i < 8; ++i) Vs[(stcol + i) * KP + row] = pv[i];
    }
    __syncthreads();
    // S_tile = Q * K^T  (wave strip: 16 q-rows x 64 kv-cols)
    f32x4 sacc[4] = {};
#pragma unroll
    for (int t = 0; t < 2; ++t)
#pragma unroll
      for (int n = 0; n < 4; ++n) {
        bf16x8 bkf = *(const bf16x8*)&Ks[(n*16 + l15) * KP + t*32 + l4*8];
        sacc[n] = mfma16(aq[t], bkf, sacc[n]);
      }
    // scale + mask
#pragma unroll
    for (int n = 0; n < 4; ++n) {
      float mk = mask[(size_t)b * S_ + kt*64 + n*16 + l15];
      float madd = (1.0f - mk) * -3.0e38f;
#pragma unroll
      for (int r = 0; r < 4; ++r) sacc[n][r] = sacc[n][r] * 0.125f + madd;
    }
    // online softmax (lane owns rows l4*4+r; cols spread over l15 within 16-group)
#pragma unroll
    for (int r = 0; r < 4; ++r) {
      float mx = fmaxf(fmaxf(sacc[0][r], sacc[1][r]), fmaxf(sacc[2][r], sacc[3][r]));
      mx = fmaxf(mx, __shfl_xor(mx, 1, 64));
      mx = fmaxf(mx, __shfl_xor(mx, 2, 64));
      mx = fmaxf(mx, __shfl_xor(mx, 4, 64));
      mx = fmaxf(mx, __shfl_xor(mx, 8, 64));
      float mnew = fmaxf(mrun[r], mx);
      float sc = __expf(mrun[r] - mnew);
      float rsum = 0.f;
#pragma unroll
      for (int n = 0; n < 4; ++n) {
        float e = __expf(sacc[n][r] - mnew);
        sacc[n][r] = e; rsum += e;
      }
      rsum += __shfl_xor(rsum, 1, 64);
      rsum += __shfl_xor(rsum, 2, 64);
      rsum += __shfl_xor(rsum, 4, 64);
      rsum += __shfl_xor(rsum, 8, 64);
      lrun[r] = lrun[r] * sc + rsum;
      mrun[r] = mnew;
#pragma unroll
      for (int n = 0; n < 4; ++n) O[n][r] *= sc;
    }
    // P -> LDS (bf16) for A-operand redistribution
#pragma unroll
    for (int n = 0; n < 4; ++n)
#pragma unroll
      for (int r = 0; r < 4; ++r)
        Pw[(l4*4 + r) * KP + n*16 + l15] = f2bf(sacc[n][r]);
    __syncthreads();
    // O += P * V
#pragma unroll
    for (int t = 0; t < 2; ++t) {
      bf16x8 ap = *(const bf16x8*)&Pw[l15 * KP + t*32 + l4*8];
#pragma unroll
      for (int n = 0; n < 4; ++n) {
        bf16x8 bvf = *(const bf16x8*)&Vs[(n*16 + l15) * KP + t*32 + l4*8];
        O[n] = mfma16(ap, bvf, O[n]);
      }
    }
  }
  // epilogue: normalize and write ctx16 (B,S,NH,HD)
#pragma unroll
  for (int r = 0; r < 4; ++r) {
    float inv = 1.0f / lrun[r];
    int s = q0 + wave*16 + l4*4 + r;
#pragma unroll
    for (int n = 0; n < 4; ++n) {
      int d = n*16 + l15;
      ctx16[((size_t)(b * S_ + s) * NH_ + h) * HD_ + d] = f2bf(O[n][r] * inv);
    }
  }
}

// ---------------- LayerNorm (in-place on d_out) ----------------

__global__ __launch_bounds__(256) void ln_kernel(float* __restrict__ x, const float* __restrict__ g,
                                                 const float* __restrict__ bb) {
  const int row = blockIdx.x, t = threadIdx.x;
  float* xr = x + (size_t)row * H_;
  f32x4 v = ((const f32x4*)xr)[t];
  float s = v.x + v.y + v.z + v.w;
  float s2 = v.x*v.x + v.y*v.y + v.z*v.z + v.w*v.w;
#pragma unroll
  for (int o = 1; o < 64; o <<= 1) { s += __shfl_xor(s, o, 64); s2 += __shfl_xor(s2, o, 64); }
  __shared__ float red[8];
  const int wave = t >> 6, lane = t & 63;
  if (lane == 0) { red[wave] = s; red[4 + wave] = s2; }
  __syncthreads();
  s = red[0] + red[1] + red[2] + red[3];
  s2 = red[4] + red[5] + red[6] + red[7];
  const float mu = s * (1.0f / H_);
  const float var = s2 * (1.0f / H_) - mu * mu;
  const float rs = rsqrtf(var + 1e-12f);
  f32x4 gg = ((const f32x4*)g)[t], bb4 = ((const f32x4*)bb)[t];
  f32x4 o;
  o.x = (v.x - mu) * rs * gg.x + bb4.x;
  o.y = (v.y - mu) * rs * gg.y + bb4.y;
  o.z = (v.z - mu) * rs * gg.z + bb4.z;
  o.w = (v.w - mu) * rs * gg.w + bb4.w;
  ((f32x4*)xr)[t] = o;
}

// ---------------- launch ----------------

extern "C" void kernel_launch(void* const* d_in, const int* in_sizes, int n_in,
                              void* d_out, int out_size, void* d_ws, size_t ws_size,
                              hipStream_t stream) {
  (void)in_sizes; (void)n_in; (void)out_size; (void)ws_size;
  const float* hs   = (const float*)d_in[0];
  const float* mask = (const float*)d_in[1];
  const float* Wq = (const float*)d_in[2];
  const float* bq = (const float*)d_in[3];
  const float* Wk = (const float*)d_in[4];
  const float* bk = (const float*)d_in[5];
  const float* Wv = (const float*)d_in[6];
  const float* bv = (const float*)d_in[7];
  const float* Wo = (const float*)d_in[8];
  const float* bo = (const float*)d_in[9];
  const float* lg = (const float*)d_in[10];
  const float* lb = (const float*)d_in[11];
  float* out = (float*)d_out;

  uint8_t* w = (uint8_t*)d_ws;
  u16* hs16  = (u16*)w;                            // 16 MB: (M,H) bf16
  u16* wt16  = (u16*)(w + ((size_t)16 << 20));     //  8 MB: 4x (N,K) bf16 W^T
  u16* qkv16 = (u16*)(w + ((size_t)24 << 20));     // 48 MB: [3][B][NH][S][HD] bf16
  u16* ctx16 = (u16*)(w + ((size_t)72 << 20));     // 16 MB: (M,H) bf16

  cvt_hs_kernel<<<dim3(M_*H_/(256*8)), dim3(256), 0, stream>>>(hs, hs16);
  cvt_wT_kernel<<<dim3(16, 16, 4), dim3(256), 0, stream>>>(Wq, Wk, Wv, Wo, wt16);
  gemm_qkv_kernel<<<dim3(24, 64), dim3(256), 0, stream>>>(hs16, wt16, bq, bk, bv, qkv16);
  attn_kernel<<<dim3(32, 16, 4), dim3(256), 0, stream>>>(qkv16, mask, ctx16);
  gemm_out_kernel<<<dim3(8, 64), dim3(256), 0, stream>>>(ctx16, wt16 + (size_t)3*H_*H_, bo, hs, out);
  ln_kernel<<<dim3(M_), dim3(256), 0, stream>>>(out, lg, lb);
}

// Round 2
// 376.514 us; speedup vs baseline: 1.2336x; 1.2336x over previous
//
#include <hip/hip_runtime.h>
#include <stdint.h>

#define H_ 1024
#define NH_ 16
#define HD_ 64
#define B_ 4
#define S_ 2048
#define M_ (B_*S_)

typedef unsigned short u16;
typedef __attribute__((ext_vector_type(8))) short bf16x8;
typedef __attribute__((ext_vector_type(4))) short s16x4;
typedef __attribute__((ext_vector_type(4))) float f32x4;
typedef __attribute__((ext_vector_type(4))) unsigned int u32x4;

#define AS1 __attribute__((address_space(1)))
#define AS3 __attribute__((address_space(3)))

__device__ __forceinline__ void gload16(const u16* g, u16* l) {
  __builtin_amdgcn_global_load_lds((AS1 void*)g, (AS3 void*)l, 16, 0, 0);
}

__device__ __forceinline__ u16 f2bf(float f) {
  union { float f; uint32_t u; } v; v.f = f;
  uint32_t u = v.u + 0x7FFFu + ((v.u >> 16) & 1u);
  return (u16)(u >> 16);
}

static __device__ __forceinline__ f32x4 mfma16(bf16x8 a, bf16x8 b, f32x4 c) {
  return __builtin_amdgcn_mfma_f32_16x16x32_bf16(a, b, c, 0, 0, 0);
}

// ---------------- conversion kernels ----------------

__global__ __launch_bounds__(256) void cvt_hs_kernel(const float* __restrict__ in, u16* __restrict__ out) {
  int i = blockIdx.x * 256 + threadIdx.x;   // each thread: 8 elems
  const f32x4* p = (const f32x4*)in;
  f32x4 a = p[2*i], b = p[2*i+1];
  u32x4 o;
  o.x = (uint32_t)f2bf(a.x) | ((uint32_t)f2bf(a.y) << 16);
  o.y = (uint32_t)f2bf(a.z) | ((uint32_t)f2bf(a.w) << 16);
  o.z = (uint32_t)f2bf(b.x) | ((uint32_t)f2bf(b.y) << 16);
  o.w = (uint32_t)f2bf(b.z) | ((uint32_t)f2bf(b.w) << 16);
  ((u32x4*)out)[i] = o;
}

// W (K x N) fp32 -> WT (N x K) bf16, for p in {q,k,v,o}
__global__ __launch_bounds__(256) void cvt_wT_kernel(const float* __restrict__ Wq, const float* __restrict__ Wk,
                                                     const float* __restrict__ Wv, const float* __restrict__ Wo,
                                                     u16* __restrict__ wt) {
  const int p = blockIdx.z;
  const float* W = (p == 0) ? Wq : (p == 1) ? Wk : (p == 2) ? Wv : Wo;
  __shared__ float tile[64][65];
  const int tr = blockIdx.y, tc = blockIdx.x, t = threadIdx.x;
#pragma unroll
  for (int it = 0; it < 16; ++it) {
    int idx = it * 256 + t, r = idx >> 6, c = idx & 63;
    tile[r][c] = W[(size_t)(tr*64 + r) * H_ + tc*64 + c];
  }
  __syncthreads();
  u16* outp = wt + (size_t)p * H_ * H_;
#pragma unroll
  for (int it = 0; it < 16; ++it) {
    int idx = it * 256 + t, r = idx >> 6, c = idx & 63;
    outp[(size_t)(tc*64 + r) * H_ + tr*64 + c] = f2bf(tile[c][r]);
  }
}

// ---------------- GEMM main loop (C = A(MxK) * Bt(NxK)^T), K=1024 ----------------
// 128x128 tile, BK=32, 4 waves (2x2), 16x16x32 MFMA. Staging via global_load_lds
// width=16 into UNPADDED [128][32] LDS (row stride 64B => b128 reads at bank floor).

__device__ __forceinline__ void gemm_tile(const u16* __restrict__ A, const u16* __restrict__ Bt,
                                          int m0, int n0, u16* As, u16* Bs, f32x4 acc[4][4]) {
  const int tid = threadIdx.x;
  const int lane = tid & 63, wave = tid >> 6;
  const int wr = wave >> 1, wc = wave & 1;
  const int l15 = lane & 15, l4 = lane >> 4;
  const int r0 = tid >> 2, c0 = (tid & 3) * 8;   // staged row (per 64-row chunk), col elem
  const u16* Ap0 = A + (size_t)(m0 + r0) * H_ + c0;
  const u16* Ap1 = A + (size_t)(m0 + 64 + r0) * H_ + c0;
  const u16* Bp0 = Bt + (size_t)(n0 + r0) * H_ + c0;
  const u16* Bp1 = Bt + (size_t)(n0 + 64 + r0) * H_ + c0;
  u16* lA0 = As + (size_t)tid * 8;
  u16* lA1 = As + 2048 + (size_t)tid * 8;
  u16* lB0 = Bs + (size_t)tid * 8;
  u16* lB1 = Bs + 2048 + (size_t)tid * 8;
  for (int k0 = 0; k0 < H_; k0 += 32) {
    __syncthreads();
    gload16(Ap0 + k0, lA0);
    gload16(Ap1 + k0, lA1);
    gload16(Bp0 + k0, lB0);
    gload16(Bp1 + k0, lB1);
    __syncthreads();   // compiler drains vmcnt(0) here -> staged data visible
    bf16x8 afr[4], bfr[4];
#pragma unroll
    for (int m = 0; m < 4; ++m) afr[m] = *(const bf16x8*)&As[(wr*64 + m*16 + l15) * 32 + l4*8];
#pragma unroll
    for (int n = 0; n < 4; ++n) bfr[n] = *(const bf16x8*)&Bs[(wc*64 + n*16 + l15) * 32 + l4*8];
#pragma unroll
    for (int m = 0; m < 4; ++m)
#pragma unroll
      for (int n = 0; n < 4; ++n)
        acc[m][n] = mfma16(afr[m], bfr[n], acc[m][n]);
  }
}

// QKV: C (8192 x 3072). Q,K scatter to [b][h][s][d]; V scatters TRANSPOSED to [b][h][d][s].
__global__ __launch_bounds__(256) void gemm_qkv_kernel(const u16* __restrict__ hs16, const u16* __restrict__ wt,
                                                       const float* __restrict__ bq, const float* __restrict__ bk,
                                                       const float* __restrict__ bv, u16* __restrict__ qkv16) {
  __shared__ __align__(16) u16 As[128*32], Bs[128*32];
  f32x4 acc[4][4] = {};
  const int m0 = blockIdx.y * 128, n0 = blockIdx.x * 128;
  gemm_tile(hs16, wt, m0, n0, As, Bs, acc);
  const int tid = threadIdx.x, lane = tid & 63, wave = tid >> 6;
  const int wr = wave >> 1, wc = wave & 1, l15 = lane & 15, l4 = lane >> 4;
  const int p = n0 >> 10;
  const float* bias = (p == 0) ? bq : (p == 1) ? bk : bv;
  u16* base = qkv16 + (size_t)p * ((size_t)B_*NH_*S_*HD_);
#pragma unroll
  for (int n = 0; n < 4; ++n) {
    int ncol = (n0 & 1023) + wc*64 + n*16 + l15;
    int h = ncol >> 6, d = ncol & 63;
    float bsv = bias[ncol];
#pragma unroll
    for (int m = 0; m < 4; ++m) {
#pragma unroll
      for (int r = 0; r < 4; ++r) {
        int row = m0 + wr*64 + m*16 + l4*4 + r;
        int b = row >> 11, s = row & 2047;
        if (p == 2)  // V transposed: [b][h][d][s]
          base[(((size_t)b*NH_ + h)*HD_ + d)*S_ + s] = f2bf(acc[m][n][r] + bsv);
        else
          base[(((size_t)b*NH_ + h)*S_ + s)*HD_ + d] = f2bf(acc[m][n][r] + bsv);
      }
    }
  }
}

// out-proj: C = ctx16 @ Wo + bo + residual(hs) -> fp32 xout
__global__ __launch_bounds__(256) void gemm_out_kernel(const u16* __restrict__ ctx16, const u16* __restrict__ wo,
                                                       const float* __restrict__ bo, const float* __restrict__ hs,
                                                       float* __restrict__ xout) {
  __shared__ __align__(16) u16 As[128*32], Bs[128*32];
  f32x4 acc[4][4] = {};
  const int m0 = blockIdx.y * 128, n0 = blockIdx.x * 128;
  gemm_tile(ctx16, wo, m0, n0, As, Bs, acc);
  const int tid = threadIdx.x, lane = tid & 63, wave = tid >> 6;
  const int wr = wave >> 1, wc = wave & 1, l15 = lane & 15, l4 = lane >> 4;
#pragma unroll
  for (int n = 0; n < 4; ++n) {
    int col = n0 + wc*64 + n*16 + l15;
    float bsv = bo[col];
#pragma unroll
    for (int m = 0; m < 4; ++m) {
#pragma unroll
      for (int r = 0; r < 4; ++r) {
        int row = m0 + wr*64 + m*16 + l4*4 + r;
        size_t off = (size_t)row * H_ + col;
        xout[off] = acc[m][n][r] + bsv + hs[off];
      }
    }
  }
}

// ---------------- flash attention ----------------
// block = (q-tile of 64 rows, head, batch); 4 waves, each wave owns 16 q-rows.
// KV tiles of 64. K and V^T staged via global_load_lds into linear [64][64] LDS with
// XOR-swizzled SOURCE addresses (chunk ^= row&7); reads apply the same XOR -> bank floor.
// P buffer padded to 76 u16/row (152B = 6 dwords mod 32 -> conflict-free scalar writes).

#define PP 76

__global__ __launch_bounds__(256) void attn_kernel(const u16* __restrict__ q_, const u16* __restrict__ k_,
                                                   const u16* __restrict__ vt_, const float* __restrict__ mask,
                                                   u16* __restrict__ ctx16) {
  __shared__ __align__(16) u16 Ks[64*64], Vs[64*64], Ps[4*16*PP];
  const int qb = blockIdx.x, h = blockIdx.y, b = blockIdx.z;
  const int tid = threadIdx.x, lane = tid & 63, wave = tid >> 6;
  const int l15 = lane & 15, l4 = lane >> 4;
  const size_t headoff = ((size_t)b * NH_ + h) * ((size_t)S_ * HD_);
  const u16* Q  = q_ + headoff;
  const u16* K  = k_ + headoff;
  const u16* Vt = vt_ + headoff;     // [d][s]
  const int q0 = qb * 64;
  bf16x8 aq[2];
#pragma unroll
  for (int t = 0; t < 2; ++t)
    aq[t] = *(const bf16x8*)(Q + (size_t)(q0 + wave*16 + l15) * HD_ + t*32 + l4*8);
  f32x4 O[4] = {};
  float mrun[4], lrun[4];
#pragma unroll
  for (int r = 0; r < 4; ++r) { mrun[r] = -1e30f; lrun[r] = 0.f; }
  const int srow = tid >> 3, sch = tid & 7;       // staging: row within 32-chunk, 16B chunk
  u16* Pw = &Ps[wave * 16 * PP];
  const float SC = 0.125f * 1.44269504f;          // scale folded with log2(e): exp2 domain
  for (int kt = 0; kt < S_/64; ++kt) {
    const u16* Kt = K + (size_t)kt * 64 * HD_;
    __syncthreads();   // all waves done reading Ks/Vs of previous tile
#pragma unroll
    for (int c = 0; c < 2; ++c) {
      int row = c*32 + srow;
      gload16(Kt + (size_t)row * HD_ + ((sch ^ (row & 7)) * 8), Ks + c*2048 + (size_t)tid*8);
      gload16(Vt + (size_t)row * S_ + kt*64 + ((sch ^ (row & 7)) * 8), Vs + c*2048 + (size_t)tid*8);
    }
    __syncthreads();   // vmcnt(0) drain -> Ks/Vs ready
    // S_tile = Q * K^T  (wave strip: 16 q-rows x 64 kv-cols)
    f32x4 sacc[4] = {};
#pragma unroll
    for (int t = 0; t < 2; ++t)
#pragma unroll
      for (int n = 0; n < 4; ++n) {
        int row = n*16 + l15;
        bf16x8 bkf = *(const bf16x8*)&Ks[row*64 + (((t*4 + l4) ^ (l15 & 7)) * 8)];
        sacc[n] = mfma16(aq[t], bkf, sacc[n]);
      }
    // scale + mask (exp2 domain)
#pragma unroll
    for (int n = 0; n < 4; ++n) {
      float mk = mask[(size_t)b * S_ + kt*64 + n*16 + l15];
      float madd = (1.0f - mk) * -3.0e38f;
#pragma unroll
      for (int r = 0; r < 4; ++r) sacc[n][r] = sacc[n][r] * SC + madd;
    }
    // online softmax (lane owns rows l4*4+r; cols spread over l15 within 16-group)
#pragma unroll
    for (int r = 0; r < 4; ++r) {
      float mx = fmaxf(fmaxf(sacc[0][r], sacc[1][r]), fmaxf(sacc[2][r], sacc[3][r]));
      mx = fmaxf(mx, __shfl_xor(mx, 1, 64));
      mx = fmaxf(mx, __shfl_xor(mx, 2, 64));
      mx = fmaxf(mx, __shfl_xor(mx, 4, 64));
      mx = fmaxf(mx, __shfl_xor(mx, 8, 64));
      float mnew = fmaxf(mrun[r], mx);
      float sc = exp2f(mrun[r] - mnew);
      float rsum = 0.f;
#pragma unroll
      for (int n = 0; n < 4; ++n) {
        float e = exp2f(sacc[n][r] - mnew);
        sacc[n][r] = e; rsum += e;
      }
      rsum += __shfl_xor(rsum, 1, 64);
      rsum += __shfl_xor(rsum, 2, 64);
      rsum += __shfl_xor(rsum, 4, 64);
      rsum += __shfl_xor(rsum, 8, 64);
      lrun[r] = lrun[r] * sc + rsum;
      mrun[r] = mnew;
#pragma unroll
      for (int n = 0; n < 4; ++n) O[n][r] *= sc;
    }
    // P -> LDS (wave-private, no barrier needed; lgkmcnt orders write->read)
#pragma unroll
    for (int n = 0; n < 4; ++n)
#pragma unroll
      for (int r = 0; r < 4; ++r)
        Pw[(l4*4 + r) * PP + n*16 + l15] = f2bf(sacc[n][r]);
    // O += P * V
#pragma unroll
    for (int t = 0; t < 2; ++t) {
      s16x4 p0 = *(const s16x4*)&Pw[l15 * PP + t*32 + l4*8];
      s16x4 p1 = *(const s16x4*)&Pw[l15 * PP + t*32 + l4*8 + 4];
      bf16x8 ap = __builtin_shufflevector(p0, p1, 0, 1, 2, 3, 4, 5, 6, 7);
#pragma unroll
      for (int n = 0; n < 4; ++n) {
        int row = n*16 + l15;
        bf16x8 bvf = *(const bf16x8*)&Vs[row*64 + (((t*4 + l4) ^ (l15 & 7)) * 8)];
        O[n] = mfma16(ap, bvf, O[n]);
      }
    }
  }
  // epilogue: normalize and write ctx16 (B,S,NH,HD)
#pragma unroll
  for (int r = 0; r < 4; ++r) {
    float inv = 1.0f / lrun[r];
    int s = q0 + wave*16 + l4*4 + r;
#pragma unroll
    for (int n = 0; n < 4; ++n) {
      int d = n*16 + l15;
      ctx16[((size_t)(b * S_ + s) * NH_ + h) * HD_ + d] = f2bf(O[n][r] * inv);
    }
  }
}

// ---------------- LayerNorm (in-place on d_out) ----------------

__global__ __launch_bounds__(256) void ln_kernel(float* __restrict__ x, const float* __restrict__ g,
                                                 const float* __restrict__ bb) {
  const int row = blockIdx.x, t = threadIdx.x;
  float* xr = x + (size_t)row * H_;
  f32x4 v = ((const f32x4*)xr)[t];
  float s = v.x + v.y + v.z + v.w;
  float s2 = v.x*v.x + v.y*v.y + v.z*v.z + v.w*v.w;
#pragma unroll
  for (int o = 1; o < 64; o <<= 1) { s += __shfl_xor(s, o, 64); s2 += __shfl_xor(s2, o, 64); }
  __shared__ float red[8];
  const int wave = t >> 6, lane = t & 63;
  if (lane == 0) { red[wave] = s; red[4 + wave] = s2; }
  __syncthreads();
  s = red[0] + red[1] + red[2] + red[3];
  s2 = red[4] + red[5] + red[6] + red[7];
  const float mu = s * (1.0f / H_);
  const float var = s2 * (1.0f / H_) - mu * mu;
  const float rs = rsqrtf(var + 1e-12f);
  f32x4 gg = ((const f32x4*)g)[t], bb4 = ((const f32x4*)bb)[t];
  f32x4 o;
  o.x = (v.x - mu) * rs * gg.x + bb4.x;
  o.y = (v.y - mu) * rs * gg.y + bb4.y;
  o.z = (v.z - mu) * rs * gg.z + bb4.z;
  o.w = (v.w - mu) * rs * gg.w + bb4.w;
  ((f32x4*)xr)[t] = o;
}

// ---------------- launch ----------------

extern "C" void kernel_launch(void* const* d_in, const int* in_sizes, int n_in,
                              void* d_out, int out_size, void* d_ws, size_t ws_size,
                              hipStream_t stream) {
  (void)in_sizes; (void)n_in; (void)out_size; (void)ws_size;
  const float* hs   = (const float*)d_in[0];
  const float* mask = (const float*)d_in[1];
  const float* Wq = (const float*)d_in[2];
  const float* bq = (const float*)d_in[3];
  const float* Wk = (const float*)d_in[4];
  const float* bk = (const float*)d_in[5];
  const float* Wv = (const float*)d_in[6];
  const float* bv = (const float*)d_in[7];
  const float* Wo = (const float*)d_in[8];
  const float* bo = (const float*)d_in[9];
  const float* lg = (const float*)d_in[10];
  const float* lb = (const float*)d_in[11];
  float* out = (float*)d_out;

  uint8_t* w = (uint8_t*)d_ws;
  u16* hs16  = (u16*)w;                            // 16 MB: (M,H) bf16
  u16* wt16  = (u16*)(w + ((size_t)16 << 20));     //  8 MB: 4x (N,K) bf16 W^T
  u16* qkv16 = (u16*)(w + ((size_t)24 << 20));     // 48 MB: Q,K [b][h][s][d]; V [b][h][d][s]
  u16* ctx16 = (u16*)(w + ((size_t)72 << 20));     // 16 MB: (M,H) bf16

  const size_t psz = (size_t)B_*NH_*S_*HD_;
  cvt_hs_kernel<<<dim3(M_*H_/(256*8)), dim3(256), 0, stream>>>(hs, hs16);
  cvt_wT_kernel<<<dim3(16, 16, 4), dim3(256), 0, stream>>>(Wq, Wk, Wv, Wo, wt16);
  gemm_qkv_kernel<<<dim3(24, 64), dim3(256), 0, stream>>>(hs16, wt16, bq, bk, bv, qkv16);
  attn_kernel<<<dim3(32, 16, 4), dim3(256), 0, stream>>>(qkv16, qkv16 + psz, qkv16 + 2*psz, mask, ctx16);
  gemm_out_kernel<<<dim3(8, 64), dim3(256), 0, stream>>>(ctx16, wt16 + (size_t)3*H_*H_, bo, hs, out);
  ln_kernel<<<dim3(M_), dim3(256), 0, stream>>>(out, lg, lb);
}

// Round 3
// 258.669 us; speedup vs baseline: 1.7956x; 1.4556x over previous
//
#include <hip/hip_runtime.h>
#include <stdint.h>

#define H_ 1024
#define NH_ 16
#define HD_ 64
#define B_ 4
#define S_ 2048
#define M_ (B_*S_)

typedef unsigned short u16;
typedef __attribute__((ext_vector_type(8))) short bf16x8;
typedef __attribute__((ext_vector_type(4))) float f32x4;
typedef __attribute__((ext_vector_type(16))) float f32x16;
typedef __attribute__((ext_vector_type(4))) unsigned int u32x4;
typedef __attribute__((ext_vector_type(4))) int i32x4;

#define AS1 __attribute__((address_space(1)))
#define AS3 __attribute__((address_space(3)))

__device__ __forceinline__ void gload16(const void* g, void* l) {
  __builtin_amdgcn_global_load_lds((const AS1 void*)g, (AS3 void*)l, 16, 0, 0);
}

__device__ __forceinline__ u16 f2bf(float f) {
  union { float f; uint32_t u; } v; v.f = f;
  uint32_t u = v.u + 0x7FFFu + ((v.u >> 16) & 1u);
  return (u16)(u >> 16);
}

static __device__ __forceinline__ f32x4 mfma16(bf16x8 a, bf16x8 b, f32x4 c) {
  return __builtin_amdgcn_mfma_f32_16x16x32_bf16(a, b, c, 0, 0, 0);
}
static __device__ __forceinline__ f32x16 mfma32(bf16x8 a, bf16x8 b, f32x16 c) {
  return __builtin_amdgcn_mfma_f32_32x32x16_bf16(a, b, c, 0, 0, 0);
}

// pack 2 f32 -> 1 dword of 2 bf16 (RNE), and 32-lane half swap
__device__ __forceinline__ int cvtpk(float lo, float hi) {
  int r;
  asm("v_cvt_pk_bf16_f32 %0, %1, %2" : "=v"(r) : "v"(lo), "v"(hi));
  return r;
}
__device__ __forceinline__ void plswap(int& a, int& b) {
  asm volatile("v_permlane32_swap_b32 %0, %1" : "+v"(a), "+v"(b));
}
#if __has_builtin(__builtin_amdgcn_exp2f)
#define EXP2F __builtin_amdgcn_exp2f
#else
#define EXP2F exp2f
#endif

// ---------------- conversion kernels ----------------

__global__ __launch_bounds__(256) void cvt_hs_kernel(const float* __restrict__ in, u16* __restrict__ out) {
  int i = blockIdx.x * 256 + threadIdx.x;   // each thread: 8 elems
  const f32x4* p = (const f32x4*)in;
  f32x4 a = p[2*i], b = p[2*i+1];
  u32x4 o;
  o.x = (uint32_t)f2bf(a.x) | ((uint32_t)f2bf(a.y) << 16);
  o.y = (uint32_t)f2bf(a.z) | ((uint32_t)f2bf(a.w) << 16);
  o.z = (uint32_t)f2bf(b.x) | ((uint32_t)f2bf(b.y) << 16);
  o.w = (uint32_t)f2bf(b.z) | ((uint32_t)f2bf(b.w) << 16);
  ((u32x4*)out)[i] = o;
}

// W (K x N) fp32 -> WT (N x K) bf16, for p in {q,k,v,o}
__global__ __launch_bounds__(256) void cvt_wT_kernel(const float* __restrict__ Wq, const float* __restrict__ Wk,
                                                     const float* __restrict__ Wv, const float* __restrict__ Wo,
                                                     u16* __restrict__ wt) {
  const int p = blockIdx.z;
  const float* W = (p == 0) ? Wq : (p == 1) ? Wk : (p == 2) ? Wv : Wo;
  __shared__ float tile[64][65];
  const int tr = blockIdx.y, tc = blockIdx.x, t = threadIdx.x;
#pragma unroll
  for (int it = 0; it < 16; ++it) {
    int idx = it * 256 + t, r = idx >> 6, c = idx & 63;
    tile[r][c] = W[(size_t)(tr*64 + r) * H_ + tc*64 + c];
  }
  __syncthreads();
  u16* outp = wt + (size_t)p * H_ * H_;
#pragma unroll
  for (int it = 0; it < 16; ++it) {
    int idx = it * 256 + t, r = idx >> 6, c = idx & 63;
    outp[(size_t)(tc*64 + r) * H_ + tr*64 + c] = f2bf(tile[c][r]);
  }
}

// ---------------- GEMM main loop (C = A(MxK) * Bt(NxK)^T), K=1024 ----------------

__device__ __forceinline__ void gemm_tile(const u16* __restrict__ A, const u16* __restrict__ Bt,
                                          int m0, int n0, u16* As, u16* Bs, f32x4 acc[4][4]) {
  const int tid = threadIdx.x;
  const int lane = tid & 63, wave = tid >> 6;
  const int wr = wave >> 1, wc = wave & 1;
  const int l15 = lane & 15, l4 = lane >> 4;
  const int r0 = tid >> 2, c0 = (tid & 3) * 8;
  const u16* Ap0 = A + (size_t)(m0 + r0) * H_ + c0;
  const u16* Ap1 = A + (size_t)(m0 + 64 + r0) * H_ + c0;
  const u16* Bp0 = Bt + (size_t)(n0 + r0) * H_ + c0;
  const u16* Bp1 = Bt + (size_t)(n0 + 64 + r0) * H_ + c0;
  u16* lA0 = As + (size_t)tid * 8;
  u16* lA1 = As + 2048 + (size_t)tid * 8;
  u16* lB0 = Bs + (size_t)tid * 8;
  u16* lB1 = Bs + 2048 + (size_t)tid * 8;
  for (int k0 = 0; k0 < H_; k0 += 32) {
    __syncthreads();
    gload16(Ap0 + k0, lA0);
    gload16(Ap1 + k0, lA1);
    gload16(Bp0 + k0, lB0);
    gload16(Bp1 + k0, lB1);
    __syncthreads();
    bf16x8 afr[4], bfr[4];
#pragma unroll
    for (int m = 0; m < 4; ++m) afr[m] = *(const bf16x8*)&As[(wr*64 + m*16 + l15) * 32 + l4*8];
#pragma unroll
    for (int n = 0; n < 4; ++n) bfr[n] = *(const bf16x8*)&Bs[(wc*64 + n*16 + l15) * 32 + l4*8];
#pragma unroll
    for (int m = 0; m < 4; ++m)
#pragma unroll
      for (int n = 0; n < 4; ++n)
        acc[m][n] = mfma16(afr[m], bfr[n], acc[m][n]);
  }
}

// QKV: C (8192 x 3072). Q,K scatter to [b][h][s][d]; V scatters TRANSPOSED to [b][h][d][s].
__global__ __launch_bounds__(256) void gemm_qkv_kernel(const u16* __restrict__ hs16, const u16* __restrict__ wt,
                                                       const float* __restrict__ bq, const float* __restrict__ bk,
                                                       const float* __restrict__ bv, u16* __restrict__ qkv16) {
  __shared__ __align__(16) u16 As[128*32], Bs[128*32];
  f32x4 acc[4][4] = {};
  const int m0 = blockIdx.y * 128, n0 = blockIdx.x * 128;
  gemm_tile(hs16, wt, m0, n0, As, Bs, acc);
  const int tid = threadIdx.x, lane = tid & 63, wave = tid >> 6;
  const int wr = wave >> 1, wc = wave & 1, l15 = lane & 15, l4 = lane >> 4;
  const int p = n0 >> 10;
  const float* bias = (p == 0) ? bq : (p == 1) ? bk : bv;
  u16* base = qkv16 + (size_t)p * ((size_t)B_*NH_*S_*HD_);
#pragma unroll
  for (int n = 0; n < 4; ++n) {
    int ncol = (n0 & 1023) + wc*64 + n*16 + l15;
    int h = ncol >> 6, d = ncol & 63;
    float bsv = bias[ncol];
#pragma unroll
    for (int m = 0; m < 4; ++m) {
#pragma unroll
      for (int r = 0; r < 4; ++r) {
        int row = m0 + wr*64 + m*16 + l4*4 + r;
        int b = row >> 11, s = row & 2047;
        if (p == 2)  // V transposed: [b][h][d][s]
          base[(((size_t)b*NH_ + h)*HD_ + d)*S_ + s] = f2bf(acc[m][n][r] + bsv);
        else
          base[(((size_t)b*NH_ + h)*S_ + s)*HD_ + d] = f2bf(acc[m][n][r] + bsv);
      }
    }
  }
}

// out-proj: C = ctx16 @ Wo + bo + residual(hs) -> fp32 xout
__global__ __launch_bounds__(256) void gemm_out_kernel(const u16* __restrict__ ctx16, const u16* __restrict__ wo,
                                                       const float* __restrict__ bo, const float* __restrict__ hs,
                                                       float* __restrict__ xout) {
  __shared__ __align__(16) u16 As[128*32], Bs[128*32];
  f32x4 acc[4][4] = {};
  const int m0 = blockIdx.y * 128, n0 = blockIdx.x * 128;
  gemm_tile(ctx16, wo, m0, n0, As, Bs, acc);
  const int tid = threadIdx.x, lane = tid & 63, wave = tid >> 6;
  const int wr = wave >> 1, wc = wave & 1, l15 = lane & 15, l4 = lane >> 4;
#pragma unroll
  for (int n = 0; n < 4; ++n) {
    int col = n0 + wc*64 + n*16 + l15;
    float bsv = bo[col];
#pragma unroll
    for (int m = 0; m < 4; ++m) {
#pragma unroll
      for (int r = 0; r < 4; ++r) {
        int row = m0 + wr*64 + m*16 + l4*4 + r;
        size_t off = (size_t)row * H_ + col;
        xout[off] = acc[m][n][r] + bsv + hs[off];
      }
    }
  }
}

// ---------------- flash attention (8 waves x 32 q-rows, swapped QK^T, in-reg softmax) ----
// Wave computes S^T[kv 64][q 32] via mfma(K, Q): lane holds all kv for q = lane&31
// (32 in-lane + 32 in lane^32). Softmax = in-reg trees + v_permlane32_swap_b32.
// P -> bf16 PV A-fragments via v_cvt_pk_bf16_f32 + permlane32_swap (T12).
// K/V^T double-buffered via global_load_lds w/ XOR source swizzle; counted vmcnt(2)
// + raw s_barrier (T4) so prefetch stays in flight across barriers.

__global__ __launch_bounds__(512) void attn_kernel(const u16* __restrict__ q_, const u16* __restrict__ k_,
                                                   const u16* __restrict__ vt_, const float* __restrict__ mask,
                                                   u16* __restrict__ ctx16) {
  __shared__ __align__(16) u16 Ks[2][64*64], Vs[2][64*64];
  __shared__ __align__(16) float Mrow[S_];
  __shared__ __align__(16) float Sc[8][32];
  const int qb = blockIdx.x, h = blockIdx.y, b = blockIdx.z;
  const int tid = threadIdx.x, lane = tid & 63, wave = tid >> 6;
  const int l31 = lane & 31, hi = lane >> 5;
  const size_t headoff = ((size_t)b * NH_ + h) * ((size_t)S_ * HD_);
  const u16* Q  = q_ + headoff;
  const u16* K  = k_ + headoff;
  const u16* Vt = vt_ + headoff;     // [d][s]
  // mask row -> madd in LDS (once per block)
  {
    f32x4 mv = *(const f32x4*)(mask + (size_t)b * S_ + tid*4);
    f32x4 md;
    md.x = (1.0f - mv.x) * -3.0e38f;
    md.y = (1.0f - mv.y) * -3.0e38f;
    md.z = (1.0f - mv.z) * -3.0e38f;
    md.w = (1.0f - mv.w) * -3.0e38f;
    *(f32x4*)&Mrow[tid*4] = md;
  }
  // Q fragments: q-row = lane&31, d-slice 16*st + 8*hi
  const int qrow = qb*256 + wave*32 + l31;
  bf16x8 qf[4];
#pragma unroll
  for (int st = 0; st < 4; ++st)
    qf[st] = *(const bf16x8*)(Q + (size_t)qrow * HD_ + st*16 + hi*8);
  f32x16 O0 = {}, O1 = {};
  float m_ = -3.0e38f, l_ = 0.f;
  const int srow = tid >> 3, sch = tid & 7;
  const int gch = sch ^ (srow & 7);           // inverse-XOR source chunk (involution)
  const int swzA = l31 & 7;                   // read-side row&7
  const float SCk = 0.125f * 1.44269504f;     // 1/sqrt(64) * log2(e)

#define STAGE(bb, kt) do { \
    const u16* Kt_ = K + (size_t)(kt) * 64 * HD_; \
    gload16(Kt_ + (size_t)srow * HD_ + gch*8, &Ks[bb][(size_t)tid*8]); \
    gload16(Vt + (size_t)srow * S_ + (kt)*64 + gch*8, &Vs[bb][(size_t)tid*8]); \
  } while (0)

  STAGE(0, 0);
  __syncthreads();   // Mrow visible + tile 0 staged (full drain, prologue only)

  for (int kt = 0; kt < 32; ++kt) {
    const int cur = kt & 1;
    const int nxt = (kt + 1) & 31;  // kt=31 stages a dummy (tile 0) to keep vmcnt uniform
    STAGE(cur ^ 1, nxt);
    asm volatile("s_waitcnt vmcnt(2)\n\ts_barrier" ::: "memory");
    // ---- QK^T: S^T[kv][q], two 32-kv tiles ----
    f32x16 s0 = {}, s1 = {};
#pragma unroll
    for (int st = 0; st < 4; ++st) {
      const int kch = ((2*st + hi) ^ swzA) * 8;
      bf16x8 kf0 = *(const bf16x8*)&Ks[cur][l31*64 + kch];
      bf16x8 kf1 = *(const bf16x8*)&Ks[cur][(32 + l31)*64 + kch];
      s0 = mfma32(kf0, qf[st], s0);
      s1 = mfma32(kf1, qf[st], s1);
    }
    // ---- scale + mask (madd broadcast quads from LDS) ----
#pragma unroll
    for (int t = 0; t < 2; ++t) {
      f32x16& ss = t ? s1 : s0;
#pragma unroll
      for (int bq = 0; bq < 4; ++bq) {
        f32x4 md = *(const f32x4*)&Mrow[kt*64 + t*32 + bq*8 + hi*4];
#pragma unroll
        for (int a2 = 0; a2 < 4; ++a2)
          ss[bq*4 + a2] = ss[bq*4 + a2] * SCk + md[a2];
      }
    }
    // ---- row max: in-reg tree + cross-half swap ----
    float v[16];
#pragma unroll
    for (int r = 0; r < 16; ++r) v[r] = fmaxf(s0[r], s1[r]);
#pragma unroll
    for (int r = 0; r < 8; ++r) v[r] = fmaxf(v[r], v[r+8]);
#pragma unroll
    for (int r = 0; r < 4; ++r) v[r] = fmaxf(v[r], v[r+4]);
    float mx = fmaxf(fmaxf(v[0], v[1]), fmaxf(v[2], v[3]));
    { int a = __float_as_int(mx), b2 = a; plswap(a, b2);
      mx = fmaxf(__int_as_float(a), __int_as_float(b2)); }
    // ---- defer-max rescale (T13) ----
    if (__any(mx > m_ + 8.f)) {
      float mnew = fmaxf(m_, mx);
      float sc = EXP2F(m_ - mnew);
      l_ *= sc;
      m_ = mnew;
      Sc[wave][l31] = sc;
#pragma unroll
      for (int bq = 0; bq < 4; ++bq) {
        f32x4 scq = *(const f32x4*)&Sc[wave][bq*8 + hi*4];
#pragma unroll
        for (int a2 = 0; a2 < 4; ++a2) { O0[bq*4+a2] *= scq[a2]; O1[bq*4+a2] *= scq[a2]; }
      }
    }
    // ---- exp + row sum ----
#pragma unroll
    for (int r = 0; r < 16; ++r) s0[r] = EXP2F(s0[r] - m_);
#pragma unroll
    for (int r = 0; r < 16; ++r) s1[r] = EXP2F(s1[r] - m_);
#pragma unroll
    for (int r = 0; r < 16; ++r) v[r] = s0[r] + s1[r];
#pragma unroll
    for (int r = 0; r < 8; ++r) v[r] += v[r+8];
#pragma unroll
    for (int r = 0; r < 4; ++r) v[r] += v[r+4];
    float rs_ = (v[0] + v[1]) + (v[2] + v[3]);
    { int a = __float_as_int(rs_), b2 = a; plswap(a, b2);
      rs_ = __int_as_float(a) + __int_as_float(b2); }
    l_ += rs_;
    // ---- pack P -> bf16 fragments (cvt_pk + permlane32_swap) and PV ----
#pragma unroll
    for (int t = 0; t < 2; ++t) {
      const f32x16& ss = t ? s1 : s0;
#pragma unroll
      for (int p = 0; p < 2; ++p) {
        int d0 = cvtpk(ss[8*p+0], ss[8*p+1]);
        int d1 = cvtpk(ss[8*p+2], ss[8*p+3]);
        int d2 = cvtpk(ss[8*p+4], ss[8*p+5]);
        int d3 = cvtpk(ss[8*p+6], ss[8*p+7]);
        plswap(d0, d2);   // d0 = frag e0-1, d2 = frag e4-5
        plswap(d1, d3);   // d1 = frag e2-3, d3 = frag e6-7
        union { i32x4 i; bf16x8 hv; } u; u.i = (i32x4){d0, d1, d2, d3};
        const int ks = 2*t + p;
        const int vch = ((2*ks + hi) ^ swzA) * 8;
        bf16x8 vb0 = *(const bf16x8*)&Vs[cur][l31*64 + vch];
        bf16x8 vb1 = *(const bf16x8*)&Vs[cur][(32 + l31)*64 + vch];
        O0 = mfma32(u.hv, vb0, O0);
        O1 = mfma32(u.hv, vb1, O1);
      }
    }
    asm volatile("s_barrier" ::: "memory");  // all waves done reading buf[cur]
  }
  asm volatile("s_waitcnt vmcnt(0)" ::: "memory");  // drain dummy stage before LDS dealloc
  // ---- epilogue: normalize (1/l broadcast to crow layout) and write ctx ----
  float invl = 1.0f / l_;
  Sc[wave][l31] = invl;
#pragma unroll
  for (int bq = 0; bq < 4; ++bq) {
    f32x4 iq = *(const f32x4*)&Sc[wave][bq*8 + hi*4];
#pragma unroll
    for (int a2 = 0; a2 < 4; ++a2) {
      int ql = 8*bq + 4*hi + a2;           // q_local = (r&3) + 8*(r>>2) + 4*hi
      int srw = qb*256 + wave*32 + ql;
      int r = bq*4 + a2;
      size_t obase = ((size_t)(b * S_ + srw) * NH_ + h) * HD_;
      ctx16[obase + l31]      = f2bf(O0[r] * iq[a2]);
      ctx16[obase + 32 + l31] = f2bf(O1[r] * iq[a2]);
    }
  }
#undef STAGE
}

// ---------------- LayerNorm (in-place on d_out) ----------------

__global__ __launch_bounds__(256) void ln_kernel(float* __restrict__ x, const float* __restrict__ g,
                                                 const float* __restrict__ bb) {
  const int row = blockIdx.x, t = threadIdx.x;
  float* xr = x + (size_t)row * H_;
  f32x4 v = ((const f32x4*)xr)[t];
  float s = v.x + v.y + v.z + v.w;
  float s2 = v.x*v.x + v.y*v.y + v.z*v.z + v.w*v.w;
#pragma unroll
  for (int o = 1; o < 64; o <<= 1) { s += __shfl_xor(s, o, 64); s2 += __shfl_xor(s2, o, 64); }
  __shared__ float red[8];
  const int wave = t >> 6, lane = t & 63;
  if (lane == 0) { red[wave] = s; red[4 + wave] = s2; }
  __syncthreads();
  s = red[0] + red[1] + red[2] + red[3];
  s2 = red[4] + red[5] + red[6] + red[7];
  const float mu = s * (1.0f / H_);
  const float var = s2 * (1.0f / H_) - mu * mu;
  const float rs = rsqrtf(var + 1e-12f);
  f32x4 gg = ((const f32x4*)g)[t], bb4 = ((const f32x4*)bb)[t];
  f32x4 o;
  o.x = (v.x - mu) * rs * gg.x + bb4.x;
  o.y = (v.y - mu) * rs * gg.y + bb4.y;
  o.z = (v.z - mu) * rs * gg.z + bb4.z;
  o.w = (v.w - mu) * rs * gg.w + bb4.w;
  ((f32x4*)xr)[t] = o;
}

// ---------------- launch ----------------

extern "C" void kernel_launch(void* const* d_in, const int* in_sizes, int n_in,
                              void* d_out, int out_size, void* d_ws, size_t ws_size,
                              hipStream_t stream) {
  (void)in_sizes; (void)n_in; (void)out_size; (void)ws_size;
  const float* hs   = (const float*)d_in[0];
  const float* mask = (const float*)d_in[1];
  const float* Wq = (const float*)d_in[2];
  const float* bq = (const float*)d_in[3];
  const float* Wk = (const float*)d_in[4];
  const float* bk = (const float*)d_in[5];
  const float* Wv = (const float*)d_in[6];
  const float* bv = (const float*)d_in[7];
  const float* Wo = (const float*)d_in[8];
  const float* bo = (const float*)d_in[9];
  const float* lg = (const float*)d_in[10];
  const float* lb = (const float*)d_in[11];
  float* out = (float*)d_out;

  uint8_t* w = (uint8_t*)d_ws;
  u16* hs16  = (u16*)w;                            // 16 MB: (M,H) bf16
  u16* wt16  = (u16*)(w + ((size_t)16 << 20));     //  8 MB: 4x (N,K) bf16 W^T
  u16* qkv16 = (u16*)(w + ((size_t)24 << 20));     // 48 MB: Q,K [b][h][s][d]; V [b][h][d][s]
  u16* ctx16 = (u16*)(w + ((size_t)72 << 20));     // 16 MB: (M,H) bf16

  const size_t psz = (size_t)B_*NH_*S_*HD_;
  cvt_hs_kernel<<<dim3(M_*H_/(256*8)), dim3(256), 0, stream>>>(hs, hs16);
  cvt_wT_kernel<<<dim3(16, 16, 4), dim3(256), 0, stream>>>(Wq, Wk, Wv, Wo, wt16);
  gemm_qkv_kernel<<<dim3(24, 64), dim3(256), 0, stream>>>(hs16, wt16, bq, bk, bv, qkv16);
  attn_kernel<<<dim3(8, 16, 4), dim3(512), 0, stream>>>(qkv16, qkv16 + psz, qkv16 + 2*psz, mask, ctx16);
  gemm_out_kernel<<<dim3(8, 64), dim3(256), 0, stream>>>(ctx16, wt16 + (size_t)3*H_*H_, bo, hs, out);
  ln_kernel<<<dim3(M_), dim3(256), 0, stream>>>(out, lg, lb);
}

// Round 4
// 254.655 us; speedup vs baseline: 1.8239x; 1.0158x over previous
//
#include <hip/hip_runtime.h>
#include <stdint.h>

#define H_ 1024
#define NH_ 16
#define HD_ 64
#define B_ 4
#define S_ 2048
#define M_ (B_*S_)

typedef unsigned short u16;
typedef __attribute__((ext_vector_type(8))) short bf16x8;
typedef __attribute__((ext_vector_type(4))) float f32x4;
typedef __attribute__((ext_vector_type(16))) float f32x16;
typedef __attribute__((ext_vector_type(4))) unsigned int u32x4;
typedef __attribute__((ext_vector_type(4))) int i32x4;

#define AS1 __attribute__((address_space(1)))
#define AS3 __attribute__((address_space(3)))

__device__ __forceinline__ void gload16(const void* g, void* l) {
  __builtin_amdgcn_global_load_lds((const AS1 void*)g, (AS3 void*)l, 16, 0, 0);
}

__device__ __forceinline__ u16 f2bf(float f) {
  union { float f; uint32_t u; } v; v.f = f;
  uint32_t u = v.u + 0x7FFFu + ((v.u >> 16) & 1u);
  return (u16)(u >> 16);
}

static __device__ __forceinline__ f32x4 mfma16(bf16x8 a, bf16x8 b, f32x4 c) {
  return __builtin_amdgcn_mfma_f32_16x16x32_bf16(a, b, c, 0, 0, 0);
}
static __device__ __forceinline__ f32x16 mfma32(bf16x8 a, bf16x8 b, f32x16 c) {
  return __builtin_amdgcn_mfma_f32_32x32x16_bf16(a, b, c, 0, 0, 0);
}

__device__ __forceinline__ int cvtpk(float lo, float hi) {
  int r;
  asm("v_cvt_pk_bf16_f32 %0, %1, %2" : "=v"(r) : "v"(lo), "v"(hi));
  return r;
}
__device__ __forceinline__ void plswap(int& a, int& b) {
  asm volatile("v_permlane32_swap_b32 %0, %1" : "+v"(a), "+v"(b));
}
#if __has_builtin(__builtin_amdgcn_exp2f)
#define EXP2F __builtin_amdgcn_exp2f
#else
#define EXP2F exp2f
#endif

// hw blockIdx -> logical id, grouping logical-contiguous blocks on one XCD (nwg%8==0)
__device__ __forceinline__ int xcd_swz(int bid, int nwg) {
  return (bid & 7) * (nwg >> 3) + (bid >> 3);
}

// ---------------- prep: hs->bf16, mask->madd + nonzero bitmap ----------------

__global__ __launch_bounds__(256) void cvt_hs_kernel(const float* __restrict__ in, u16* __restrict__ out,
                                                     const float* __restrict__ mask, float* __restrict__ madd_g,
                                                     uint32_t* __restrict__ nzbits) {
  const int bid = blockIdx.x;
  if (bid < M_*H_/(256*8)) {
    int i = bid * 256 + threadIdx.x;   // each thread: 8 elems
    const f32x4* p = (const f32x4*)in;
    f32x4 a = p[2*i], b = p[2*i+1];
    u32x4 o;
    o.x = (uint32_t)f2bf(a.x) | ((uint32_t)f2bf(a.y) << 16);
    o.y = (uint32_t)f2bf(a.z) | ((uint32_t)f2bf(a.w) << 16);
    o.z = (uint32_t)f2bf(b.x) | ((uint32_t)f2bf(b.y) << 16);
    o.w = (uint32_t)f2bf(b.z) | ((uint32_t)f2bf(b.w) << 16);
    ((u32x4*)out)[i] = o;
  } else {
    const int mb = bid - M_*H_/(256*8);       // 0..3
    int i = mb * 256 + threadIdx.x;           // 1024 threads x 8 = 8192 mask elems
    f32x4 a = ((const f32x4*)mask)[2*i], b4 = ((const f32x4*)mask)[2*i+1];
    f32x4 ma, mb4;
    ma.x = (1.0f - a.x) * -3.0e38f;  ma.y = (1.0f - a.y) * -3.0e38f;
    ma.z = (1.0f - a.z) * -3.0e38f;  ma.w = (1.0f - a.w) * -3.0e38f;
    mb4.x = (1.0f - b4.x) * -3.0e38f; mb4.y = (1.0f - b4.y) * -3.0e38f;
    mb4.z = (1.0f - b4.z) * -3.0e38f; mb4.w = (1.0f - b4.w) * -3.0e38f;
    ((f32x4*)madd_g)[2*i] = ma;  ((f32x4*)madd_g)[2*i+1] = mb4;
    if (mb == 0) {  // per-(b, kv-tile) nonzero flags
      const int t = threadIdx.x;
      if (t < B_) nzbits[t] = 0u;
      __syncthreads();
      if (t < B_*32) {
        int b = t >> 5, kt = t & 31;
        const float* mrow = mask + (size_t)b * S_ + kt*64;
        uint32_t nz = 0;
        for (int c = 0; c < 64; ++c) nz |= (mrow[c] != 1.0f) ? 1u : 0u;
        if (nz) atomicOr(&nzbits[b], 1u << kt);
      }
    }
  }
}

// W (K x N) fp32 -> WT (N x K) bf16, for p in {q,k,v,o}
__global__ __launch_bounds__(256) void cvt_wT_kernel(const float* __restrict__ Wq, const float* __restrict__ Wk,
                                                     const float* __restrict__ Wv, const float* __restrict__ Wo,
                                                     u16* __restrict__ wt) {
  const int p = blockIdx.z;
  const float* W = (p == 0) ? Wq : (p == 1) ? Wk : (p == 2) ? Wv : Wo;
  __shared__ float tile[64][65];
  const int tr = blockIdx.y, tc = blockIdx.x, t = threadIdx.x;
#pragma unroll
  for (int it = 0; it < 16; ++it) {
    int idx = it * 256 + t, r = idx >> 6, c = idx & 63;
    tile[r][c] = W[(size_t)(tr*64 + r) * H_ + tc*64 + c];
  }
  __syncthreads();
  u16* outp = wt + (size_t)p * H_ * H_;
#pragma unroll
  for (int it = 0; it < 16; ++it) {
    int idx = it * 256 + t, r = idx >> 6, c = idx & 63;
    outp[(size_t)(tc*64 + r) * H_ + tr*64 + c] = f2bf(tile[c][r]);
  }
}

// ---------------- GEMM main loop (C = A(MxK) * Bt(NxK)^T), K=1024 ----------------

__device__ __forceinline__ void gemm_tile(const u16* __restrict__ A, const u16* __restrict__ Bt,
                                          int m0, int n0, u16* As, u16* Bs, f32x4 acc[4][4]) {
  const int tid = threadIdx.x;
  const int lane = tid & 63, wave = tid >> 6;
  const int wr = wave >> 1, wc = wave & 1;
  const int l15 = lane & 15, l4 = lane >> 4;
  const int r0 = tid >> 2, c0 = (tid & 3) * 8;
  const u16* Ap0 = A + (size_t)(m0 + r0) * H_ + c0;
  const u16* Ap1 = A + (size_t)(m0 + 64 + r0) * H_ + c0;
  const u16* Bp0 = Bt + (size_t)(n0 + r0) * H_ + c0;
  const u16* Bp1 = Bt + (size_t)(n0 + 64 + r0) * H_ + c0;
  u16* lA0 = As + (size_t)tid * 8;
  u16* lA1 = As + 2048 + (size_t)tid * 8;
  u16* lB0 = Bs + (size_t)tid * 8;
  u16* lB1 = Bs + 2048 + (size_t)tid * 8;
  for (int k0 = 0; k0 < H_; k0 += 32) {
    __syncthreads();
    gload16(Ap0 + k0, lA0);
    gload16(Ap1 + k0, lA1);
    gload16(Bp0 + k0, lB0);
    gload16(Bp1 + k0, lB1);
    __syncthreads();
    bf16x8 afr[4], bfr[4];
#pragma unroll
    for (int m = 0; m < 4; ++m) afr[m] = *(const bf16x8*)&As[(wr*64 + m*16 + l15) * 32 + l4*8];
#pragma unroll
    for (int n = 0; n < 4; ++n) bfr[n] = *(const bf16x8*)&Bs[(wc*64 + n*16 + l15) * 32 + l4*8];
#pragma unroll
    for (int m = 0; m < 4; ++m)
#pragma unroll
      for (int n = 0; n < 4; ++n)
        acc[m][n] = mfma16(afr[m], bfr[n], acc[m][n]);
  }
}

// QKV: C (8192 x 3072). Q (prescaled by 0.125*log2e), K -> [b][h][s][d]; V -> [b][h][d][s].
__global__ __launch_bounds__(256) void gemm_qkv_kernel(const u16* __restrict__ hs16, const u16* __restrict__ wt,
                                                       const float* __restrict__ bq, const float* __restrict__ bk,
                                                       const float* __restrict__ bv, u16* __restrict__ qkv16) {
  __shared__ __align__(16) u16 As[128*32], Bs[128*32];
  f32x4 acc[4][4] = {};
  const int lg = xcd_swz(blockIdx.x, 1536);
  const int m0 = (lg / 24) * 128, n0 = (lg % 24) * 128;
  gemm_tile(hs16, wt, m0, n0, As, Bs, acc);
  const int tid = threadIdx.x, lane = tid & 63, wave = tid >> 6;
  const int wr = wave >> 1, wc = wave & 1, l15 = lane & 15, l4 = lane >> 4;
  const int p = n0 >> 10;
  const float* bias = (p == 0) ? bq : (p == 1) ? bk : bv;
  const float qsc = (p == 0) ? 0.18033688f : 1.0f;   // 0.125 * log2(e)
  u16* base = qkv16 + (size_t)p * ((size_t)B_*NH_*S_*HD_);
#pragma unroll
  for (int n = 0; n < 4; ++n) {
    int ncol = (n0 & 1023) + wc*64 + n*16 + l15;
    int h = ncol >> 6, d = ncol & 63;
    float bsv = bias[ncol];
#pragma unroll
    for (int m = 0; m < 4; ++m) {
#pragma unroll
      for (int r = 0; r < 4; ++r) {
        int row = m0 + wr*64 + m*16 + l4*4 + r;
        int b = row >> 11, s = row & 2047;
        float val = (acc[m][n][r] + bsv) * qsc;
        if (p == 2)  // V transposed: [b][h][d][s]
          base[(((size_t)b*NH_ + h)*HD_ + d)*S_ + s] = f2bf(val);
        else
          base[(((size_t)b*NH_ + h)*S_ + s)*HD_ + d] = f2bf(val);
      }
    }
  }
}

// out-proj: C = ctx16 @ Wo + bo + residual(hs) -> fp32 xout
__global__ __launch_bounds__(256) void gemm_out_kernel(const u16* __restrict__ ctx16, const u16* __restrict__ wo,
                                                       const float* __restrict__ bo, const float* __restrict__ hs,
                                                       float* __restrict__ xout) {
  __shared__ __align__(16) u16 As[128*32], Bs[128*32];
  f32x4 acc[4][4] = {};
  const int lg = xcd_swz(blockIdx.x, 512);
  const int m0 = (lg / 8) * 128, n0 = (lg % 8) * 128;
  gemm_tile(ctx16, wo, m0, n0, As, Bs, acc);
  const int tid = threadIdx.x, lane = tid & 63, wave = tid >> 6;
  const int wr = wave >> 1, wc = wave & 1, l15 = lane & 15, l4 = lane >> 4;
#pragma unroll
  for (int n = 0; n < 4; ++n) {
    int col = n0 + wc*64 + n*16 + l15;
    float bsv = bo[col];
#pragma unroll
    for (int m = 0; m < 4; ++m) {
#pragma unroll
      for (int r = 0; r < 4; ++r) {
        int row = m0 + wr*64 + m*16 + l4*4 + r;
        size_t off = (size_t)row * H_ + col;
        xout[off] = acc[m][n][r] + bsv + hs[off];
      }
    }
  }
}

// ---------------- flash attention (4 waves x 32 q-rows, swapped QK^T, in-reg softmax) ----
// Q prescaled (exp2 domain). Mask handled via precomputed madd + per-tile nonzero bitmap
// (skipped entirely when tile is unmasked). LDS 33.3KB -> 4 blocks/CU; XCD swizzle groups
// same-(b,h) blocks per XCD for K/V L2 reuse. Counted vmcnt(4) double-buffer.

__global__ __launch_bounds__(256) void attn_kernel(const u16* __restrict__ q_, const u16* __restrict__ k_,
                                                   const u16* __restrict__ vt_, const float* __restrict__ madd_g,
                                                   const uint32_t* __restrict__ nzbits,
                                                   u16* __restrict__ ctx16) {
  __shared__ __align__(16) u16 Ks[2][64*64], Vs[2][64*64];
  __shared__ __align__(16) float Sc[4][32];
  const int lgid = xcd_swz(blockIdx.x, 1024);
  const int qb = lgid & 15, bh = lgid >> 4, h = bh & 15, b = bh >> 4;
  const int tid = threadIdx.x, lane = tid & 63, wave = tid >> 6;
  const int l31 = lane & 31, hi = lane >> 5;
  const size_t headoff = ((size_t)b * NH_ + h) * ((size_t)S_ * HD_);
  const u16* Q  = q_ + headoff;
  const u16* K  = k_ + headoff;
  const u16* Vt = vt_ + headoff;     // [d][s]
  const uint32_t nzb = nzbits[b];
  // Q fragments: q-row = lane&31, d-slice 16*st + 8*hi
  const int qrow = qb*128 + wave*32 + l31;
  bf16x8 qf[4];
#pragma unroll
  for (int st = 0; st < 4; ++st)
    qf[st] = *(const bf16x8*)(Q + (size_t)qrow * HD_ + st*16 + hi*8);
  f32x16 O0 = {}, O1 = {};
  float m_ = -3.0e38f, l_ = 0.f;
  const int srow = tid >> 3, sch = tid & 7;
  const int gch = sch ^ (srow & 7);           // inverse-XOR source chunk (involution)
  const int swzA = l31 & 7;                   // read-side row&7

#define STAGE(bb, kt) do { \
    const u16* Kt_ = K + (size_t)(kt) * 64 * HD_; \
    _Pragma("unroll") \
    for (int c = 0; c < 2; ++c) { \
      int row = c*32 + srow; \
      gload16(Kt_ + (size_t)row * HD_ + gch*8, &Ks[bb][c*2048 + (size_t)tid*8]); \
      gload16(Vt + (size_t)row * S_ + (kt)*64 + gch*8, &Vs[bb][c*2048 + (size_t)tid*8]); \
    } \
  } while (0)

  STAGE(0, 0);
  __syncthreads();   // prologue full drain: tile 0 staged

  for (int kt = 0; kt < 32; ++kt) {
    const int cur = kt & 1;
    const int nxt = (kt + 1) & 31;  // kt=31 stages a dummy (tile 0) to keep vmcnt uniform
    STAGE(cur ^ 1, nxt);
    asm volatile("s_waitcnt vmcnt(4)\n\ts_barrier" ::: "memory");
    // ---- QK^T: S^T[kv][q], two 32-kv tiles (Q prescaled -> output already in exp2 domain)
    f32x16 s0 = {}, s1 = {};
#pragma unroll
    for (int st = 0; st < 4; ++st) {
      const int kch = ((2*st + hi) ^ swzA) * 8;
      bf16x8 kf0 = *(const bf16x8*)&Ks[cur][l31*64 + kch];
      bf16x8 kf1 = *(const bf16x8*)&Ks[cur][(32 + l31)*64 + kch];
      s0 = mfma32(kf0, qf[st], s0);
      s1 = mfma32(kf1, qf[st], s1);
    }
    // ---- mask add, only when this kv-tile has masked columns ----
    if ((nzb >> kt) & 1u) {
#pragma unroll
      for (int t = 0; t < 2; ++t) {
        f32x16& ss = t ? s1 : s0;
#pragma unroll
        for (int bq = 0; bq < 4; ++bq) {
          f32x4 md = *(const f32x4*)(madd_g + (size_t)b * S_ + kt*64 + t*32 + bq*8 + hi*4);
#pragma unroll
          for (int a2 = 0; a2 < 4; ++a2) ss[bq*4 + a2] += md[a2];
        }
      }
    }
    // ---- row max: in-reg tree + cross-half swap ----
    float v[16];
#pragma unroll
    for (int r = 0; r < 16; ++r) v[r] = fmaxf(s0[r], s1[r]);
#pragma unroll
    for (int r = 0; r < 8; ++r) v[r] = fmaxf(v[r], v[r+8]);
#pragma unroll
    for (int r = 0; r < 4; ++r) v[r] = fmaxf(v[r], v[r+4]);
    float mx = fmaxf(fmaxf(v[0], v[1]), fmaxf(v[2], v[3]));
    { int a = __float_as_int(mx), b2 = a; plswap(a, b2);
      mx = fmaxf(__int_as_float(a), __int_as_float(b2)); }
    // ---- defer-max rescale (T13, THR=8 in log2 units -> P bounded by 256) ----
    if (__any(mx > m_ + 8.f)) {
      float mnew = fmaxf(m_, mx);
      float sc = EXP2F(m_ - mnew);
      l_ *= sc;
      m_ = mnew;
      Sc[wave][l31] = sc;
#pragma unroll
      for (int bq = 0; bq < 4; ++bq) {
        f32x4 scq = *(const f32x4*)&Sc[wave][bq*8 + hi*4];
#pragma unroll
        for (int a2 = 0; a2 < 4; ++a2) { O0[bq*4+a2] *= scq[a2]; O1[bq*4+a2] *= scq[a2]; }
      }
    }
    // ---- exp2 + row sum ----
#pragma unroll
    for (int r = 0; r < 16; ++r) s0[r] = EXP2F(s0[r] - m_);
#pragma unroll
    for (int r = 0; r < 16; ++r) s1[r] = EXP2F(s1[r] - m_);
#pragma unroll
    for (int r = 0; r < 16; ++r) v[r] = s0[r] + s1[r];
#pragma unroll
    for (int r = 0; r < 8; ++r) v[r] += v[r+8];
#pragma unroll
    for (int r = 0; r < 4; ++r) v[r] += v[r+4];
    float rs_ = (v[0] + v[1]) + (v[2] + v[3]);
    { int a = __float_as_int(rs_), b2 = a; plswap(a, b2);
      rs_ = __int_as_float(a) + __int_as_float(b2); }
    l_ += rs_;
    // ---- pack P -> bf16 fragments (cvt_pk + permlane32_swap) and PV ----
#pragma unroll
    for (int t = 0; t < 2; ++t) {
      const f32x16& ss = t ? s1 : s0;
#pragma unroll
      for (int p = 0; p < 2; ++p) {
        int d0 = cvtpk(ss[8*p+0], ss[8*p+1]);
        int d1 = cvtpk(ss[8*p+2], ss[8*p+3]);
        int d2 = cvtpk(ss[8*p+4], ss[8*p+5]);
        int d3 = cvtpk(ss[8*p+6], ss[8*p+7]);
        plswap(d0, d2);   // d0 = frag e0-1, d2 = frag e4-5
        plswap(d1, d3);   // d1 = frag e2-3, d3 = frag e6-7
        union { i32x4 i; bf16x8 hv; } u; u.i = (i32x4){d0, d1, d2, d3};
        const int ks = 2*t + p;
        const int vch = ((2*ks + hi) ^ swzA) * 8;
        bf16x8 vb0 = *(const bf16x8*)&Vs[cur][l31*64 + vch];
        bf16x8 vb1 = *(const bf16x8*)&Vs[cur][(32 + l31)*64 + vch];
        O0 = mfma32(u.hv, vb0, O0);
        O1 = mfma32(u.hv, vb1, O1);
      }
    }
    asm volatile("s_barrier" ::: "memory");  // all waves done reading buf[cur]
  }
  asm volatile("s_waitcnt vmcnt(0)" ::: "memory");  // drain dummy stage before LDS dealloc
  // ---- epilogue: normalize (1/l broadcast to crow layout) and write ctx ----
  float invl = 1.0f / l_;
  Sc[wave][l31] = invl;
#pragma unroll
  for (int bq = 0; bq < 4; ++bq) {
    f32x4 iq = *(const f32x4*)&Sc[wave][bq*8 + hi*4];
#pragma unroll
    for (int a2 = 0; a2 < 4; ++a2) {
      int ql = 8*bq + 4*hi + a2;           // q_local = (r&3) + 8*(r>>2) + 4*hi
      int srw = qb*128 + wave*32 + ql;
      int r = bq*4 + a2;
      size_t obase = ((size_t)(b * S_ + srw) * NH_ + h) * HD_;
      ctx16[obase + l31]      = f2bf(O0[r] * iq[a2]);
      ctx16[obase + 32 + l31] = f2bf(O1[r] * iq[a2]);
    }
  }
#undef STAGE
}

// ---------------- LayerNorm (in-place on d_out) ----------------

__global__ __launch_bounds__(256) void ln_kernel(float* __restrict__ x, const float* __restrict__ g,
                                                 const float* __restrict__ bb) {
  const int row = blockIdx.x, t = threadIdx.x;
  float* xr = x + (size_t)row * H_;
  f32x4 v = ((const f32x4*)xr)[t];
  float s = v.x + v.y + v.z + v.w;
  float s2 = v.x*v.x + v.y*v.y + v.z*v.z + v.w*v.w;
#pragma unroll
  for (int o = 1; o < 64; o <<= 1) { s += __shfl_xor(s, o, 64); s2 += __shfl_xor(s2, o, 64); }
  __shared__ float red[8];
  const int wave = t >> 6, lane = t & 63;
  if (lane == 0) { red[wave] = s; red[4 + wave] = s2; }
  __syncthreads();
  s = red[0] + red[1] + red[2] + red[3];
  s2 = red[4] + red[5] + red[6] + red[7];
  const float mu = s * (1.0f / H_);
  const float var = s2 * (1.0f / H_) - mu * mu;
  const float rs = rsqrtf(var + 1e-12f);
  f32x4 gg = ((const f32x4*)g)[t], bb4 = ((const f32x4*)bb)[t];
  f32x4 o;
  o.x = (v.x - mu) * rs * gg.x + bb4.x;
  o.y = (v.y - mu) * rs * gg.y + bb4.y;
  o.z = (v.z - mu) * rs * gg.z + bb4.z;
  o.w = (v.w - mu) * rs * gg.w + bb4.w;
  ((f32x4*)xr)[t] = o;
}

// ---------------- launch ----------------

extern "C" void kernel_launch(void* const* d_in, const int* in_sizes, int n_in,
                              void* d_out, int out_size, void* d_ws, size_t ws_size,
                              hipStream_t stream) {
  (void)in_sizes; (void)n_in; (void)out_size; (void)ws_size;
  const float* hs   = (const float*)d_in[0];
  const float* mask = (const float*)d_in[1];
  const float* Wq = (const float*)d_in[2];
  const float* bq = (const float*)d_in[3];
  const float* Wk = (const float*)d_in[4];
  const float* bk = (const float*)d_in[5];
  const float* Wv = (const float*)d_in[6];
  const float* bv = (const float*)d_in[7];
  const float* Wo = (const float*)d_in[8];
  const float* bo = (const float*)d_in[9];
  const float* lg = (const float*)d_in[10];
  const float* lb = (const float*)d_in[11];
  float* out = (float*)d_out;

  uint8_t* w = (uint8_t*)d_ws;
  u16* hs16  = (u16*)w;                                 // 16 MB: (M,H) bf16
  u16* wt16  = (u16*)(w + ((size_t)16 << 20));          //  8 MB: 4x (N,K) bf16 W^T
  u16* qkv16 = (u16*)(w + ((size_t)24 << 20));          // 48 MB: Q,K [b][h][s][d]; V [b][h][d][s]
  u16* ctx16 = (u16*)(w + ((size_t)72 << 20));          // 16 MB: (M,H) bf16
  float* madd_g = (float*)(w + ((size_t)88 << 20));     // 32 KB: (B,S) mask add
  uint32_t* nzbits = (uint32_t*)(w + ((size_t)88 << 20) + 32768);  // 16 B

  const size_t psz = (size_t)B_*NH_*S_*HD_;
  cvt_hs_kernel<<<dim3(M_*H_/(256*8) + 4), dim3(256), 0, stream>>>(hs, hs16, mask, madd_g, nzbits);
  cvt_wT_kernel<<<dim3(16, 16, 4), dim3(256), 0, stream>>>(Wq, Wk, Wv, Wo, wt16);
  gemm_qkv_kernel<<<dim3(1536), dim3(256), 0, stream>>>(hs16, wt16, bq, bk, bv, qkv16);
  attn_kernel<<<dim3(1024), dim3(256), 0, stream>>>(qkv16, qkv16 + psz, qkv16 + 2*psz, madd_g, nzbits, ctx16);
  gemm_out_kernel<<<dim3(512), dim3(256), 0, stream>>>(ctx16, wt16 + (size_t)3*H_*H_, bo, hs, out);
  ln_kernel<<<dim3(M_), dim3(256), 0, stream>>>(out, lg, lb);
}

// Round 5
// 225.788 us; speedup vs baseline: 2.0571x; 1.1278x over previous
//
#include <hip/hip_runtime.h>
#include <stdint.h>

#define H_ 1024
#define NH_ 16
#define HD_ 64
#define B_ 4
#define S_ 2048
#define M_ (B_*S_)

typedef unsigned short u16;
typedef __attribute__((ext_vector_type(4))) unsigned short u16x4;
typedef __attribute__((ext_vector_type(8))) short bf16x8;
typedef __attribute__((ext_vector_type(4))) float f32x4;
typedef __attribute__((ext_vector_type(16))) float f32x16;
typedef __attribute__((ext_vector_type(4))) unsigned int u32x4;
typedef __attribute__((ext_vector_type(4))) int i32x4;

#define AS1 __attribute__((address_space(1)))
#define AS3 __attribute__((address_space(3)))

__device__ __forceinline__ void gload16(const void* g, void* l) {
  __builtin_amdgcn_global_load_lds((const AS1 void*)g, (AS3 void*)l, 16, 0, 0);
}

__device__ __forceinline__ u16 f2bf(float f) {
  union { float f; uint32_t u; } v; v.f = f;
  uint32_t u = v.u + 0x7FFFu + ((v.u >> 16) & 1u);
  return (u16)(u >> 16);
}

static __device__ __forceinline__ f32x4 mfma16(bf16x8 a, bf16x8 b, f32x4 c) {
  return __builtin_amdgcn_mfma_f32_16x16x32_bf16(a, b, c, 0, 0, 0);
}
static __device__ __forceinline__ f32x16 mfma32(bf16x8 a, bf16x8 b, f32x16 c) {
  return __builtin_amdgcn_mfma_f32_32x32x16_bf16(a, b, c, 0, 0, 0);
}

__device__ __forceinline__ int cvtpk(float lo, float hi) {
  int r;
  asm("v_cvt_pk_bf16_f32 %0, %1, %2" : "=v"(r) : "v"(lo), "v"(hi));
  return r;
}
__device__ __forceinline__ void plswap(int& a, int& b) {
  asm volatile("v_permlane32_swap_b32 %0, %1" : "+v"(a), "+v"(b));
}
#if __has_builtin(__builtin_amdgcn_exp2f)
#define EXP2F __builtin_amdgcn_exp2f
#else
#define EXP2F exp2f
#endif

// hw blockIdx -> logical id, grouping logical-contiguous blocks on one XCD (nwg%8==0)
__device__ __forceinline__ int xcd_swz(int bid, int nwg) {
  return (bid & 7) * (nwg >> 3) + (bid >> 3);
}

// ---------------- prep: hs->bf16, mask->madd + nonzero bitmap ----------------

__global__ __launch_bounds__(256) void cvt_hs_kernel(const float* __restrict__ in, u16* __restrict__ out,
                                                     const float* __restrict__ mask, float* __restrict__ madd_g,
                                                     uint32_t* __restrict__ nzbits) {
  const int bid = blockIdx.x;
  if (bid < M_*H_/(256*8)) {
    int i = bid * 256 + threadIdx.x;   // each thread: 8 elems
    const f32x4* p = (const f32x4*)in;
    f32x4 a = p[2*i], b = p[2*i+1];
    u32x4 o;
    o.x = (uint32_t)f2bf(a.x) | ((uint32_t)f2bf(a.y) << 16);
    o.y = (uint32_t)f2bf(a.z) | ((uint32_t)f2bf(a.w) << 16);
    o.z = (uint32_t)f2bf(b.x) | ((uint32_t)f2bf(b.y) << 16);
    o.w = (uint32_t)f2bf(b.z) | ((uint32_t)f2bf(b.w) << 16);
    ((u32x4*)out)[i] = o;
  } else {
    const int mb = bid - M_*H_/(256*8);       // 0..3
    int i = mb * 256 + threadIdx.x;           // 1024 threads x 8 = 8192 mask elems
    f32x4 a = ((const f32x4*)mask)[2*i], b4 = ((const f32x4*)mask)[2*i+1];
    f32x4 ma, mb4;
    ma.x = (1.0f - a.x) * -3.0e38f;  ma.y = (1.0f - a.y) * -3.0e38f;
    ma.z = (1.0f - a.z) * -3.0e38f;  ma.w = (1.0f - a.w) * -3.0e38f;
    mb4.x = (1.0f - b4.x) * -3.0e38f; mb4.y = (1.0f - b4.y) * -3.0e38f;
    mb4.z = (1.0f - b4.z) * -3.0e38f; mb4.w = (1.0f - b4.w) * -3.0e38f;
    ((f32x4*)madd_g)[2*i] = ma;  ((f32x4*)madd_g)[2*i+1] = mb4;
    if (mb == 0) {  // per-(b, kv-tile) nonzero flags
      const int t = threadIdx.x;
      if (t < B_) nzbits[t] = 0u;
      __syncthreads();
      if (t < B_*32) {
        int b = t >> 5, kt = t & 31;
        const float* mrow = mask + (size_t)b * S_ + kt*64;
        uint32_t nz = 0;
        for (int c = 0; c < 64; ++c) nz |= (mrow[c] != 1.0f) ? 1u : 0u;
        if (nz) atomicOr(&nzbits[b], 1u << kt);
      }
    }
  }
}

// W (K x N) fp32 -> WT (N x K) bf16, for p in {q,k,v,o}
__global__ __launch_bounds__(256) void cvt_wT_kernel(const float* __restrict__ Wq, const float* __restrict__ Wk,
                                                     const float* __restrict__ Wv, const float* __restrict__ Wo,
                                                     u16* __restrict__ wt) {
  const int p = blockIdx.z;
  const float* W = (p == 0) ? Wq : (p == 1) ? Wk : (p == 2) ? Wv : Wo;
  __shared__ float tile[64][65];
  const int tr = blockIdx.y, tc = blockIdx.x, t = threadIdx.x;
#pragma unroll
  for (int it = 0; it < 16; ++it) {
    int idx = it * 256 + t, r = idx >> 6, c = idx & 63;
    tile[r][c] = W[(size_t)(tr*64 + r) * H_ + tc*64 + c];
  }
  __syncthreads();
  u16* outp = wt + (size_t)p * H_ * H_;
#pragma unroll
  for (int it = 0; it < 16; ++it) {
    int idx = it * 256 + t, r = idx >> 6, c = idx & 63;
    outp[(size_t)(tc*64 + r) * H_ + tr*64 + c] = f2bf(tile[c][r]);
  }
}

// ---------------- GEMM main loop (C = A(MxK) * Bt(NxK)^T), K=1024 ----------------

__device__ __forceinline__ void gemm_tile(const u16* __restrict__ A, const u16* __restrict__ Bt,
                                          int m0, int n0, u16* As, u16* Bs, f32x4 acc[4][4]) {
  const int tid = threadIdx.x;
  const int lane = tid & 63, wave = tid >> 6;
  const int wr = wave >> 1, wc = wave & 1;
  const int l15 = lane & 15, l4 = lane >> 4;
  const int r0 = tid >> 2, c0 = (tid & 3) * 8;
  const u16* Ap0 = A + (size_t)(m0 + r0) * H_ + c0;
  const u16* Ap1 = A + (size_t)(m0 + 64 + r0) * H_ + c0;
  const u16* Bp0 = Bt + (size_t)(n0 + r0) * H_ + c0;
  const u16* Bp1 = Bt + (size_t)(n0 + 64 + r0) * H_ + c0;
  u16* lA0 = As + (size_t)tid * 8;
  u16* lA1 = As + 2048 + (size_t)tid * 8;
  u16* lB0 = Bs + (size_t)tid * 8;
  u16* lB1 = Bs + 2048 + (size_t)tid * 8;
  for (int k0 = 0; k0 < H_; k0 += 32) {
    __syncthreads();
    gload16(Ap0 + k0, lA0);
    gload16(Ap1 + k0, lA1);
    gload16(Bp0 + k0, lB0);
    gload16(Bp1 + k0, lB1);
    __syncthreads();
    bf16x8 afr[4], bfr[4];
#pragma unroll
    for (int m = 0; m < 4; ++m) afr[m] = *(const bf16x8*)&As[(wr*64 + m*16 + l15) * 32 + l4*8];
#pragma unroll
    for (int n = 0; n < 4; ++n) bfr[n] = *(const bf16x8*)&Bs[(wc*64 + n*16 + l15) * 32 + l4*8];
#pragma unroll
    for (int m = 0; m < 4; ++m)
#pragma unroll
      for (int n = 0; n < 4; ++n)
        acc[m][n] = mfma16(afr[m], bfr[n], acc[m][n]);
  }
}

// QKV: C (8192 x 3072). Q (prescaled by 0.125*log2e), K -> [b][h][s][d]; V -> [b][h][d][s]
// with V^T stores packed u16x4 along s (r=0..3 contiguous) to cut write amplification.
__global__ __launch_bounds__(256) void gemm_qkv_kernel(const u16* __restrict__ hs16, const u16* __restrict__ wt,
                                                       const float* __restrict__ bq, const float* __restrict__ bk,
                                                       const float* __restrict__ bv, u16* __restrict__ qkv16) {
  __shared__ __align__(16) u16 As[128*32], Bs[128*32];
  f32x4 acc[4][4] = {};
  const int lg = xcd_swz(blockIdx.x, 1536);
  const int m0 = (lg / 24) * 128, n0 = (lg % 24) * 128;
  gemm_tile(hs16, wt, m0, n0, As, Bs, acc);
  const int tid = threadIdx.x, lane = tid & 63, wave = tid >> 6;
  const int wr = wave >> 1, wc = wave & 1, l15 = lane & 15, l4 = lane >> 4;
  const int p = n0 >> 10;
  const float* bias = (p == 0) ? bq : (p == 1) ? bk : bv;
  const float qsc = (p == 0) ? 0.18033688f : 1.0f;   // 0.125 * log2(e)
  u16* base = qkv16 + (size_t)p * ((size_t)B_*NH_*S_*HD_);
  if (p == 2) {
    const int b = m0 >> 11;
#pragma unroll
    for (int n = 0; n < 4; ++n) {
      int ncol = (n0 & 1023) + wc*64 + n*16 + l15;
      int h = ncol >> 6, d = ncol & 63;
      float bsv = bias[ncol];
#pragma unroll
      for (int m = 0; m < 4; ++m) {
        int s0 = (m0 & 2047) + wr*64 + m*16 + l4*4;
        u16x4 pk;
#pragma unroll
        for (int r = 0; r < 4; ++r) pk[r] = f2bf(acc[m][n][r] + bsv);
        *(u16x4*)(base + (((size_t)b*NH_ + h)*HD_ + d)*S_ + s0) = pk;
      }
    }
  } else {
#pragma unroll
    for (int n = 0; n < 4; ++n) {
      int ncol = (n0 & 1023) + wc*64 + n*16 + l15;
      int h = ncol >> 6, d = ncol & 63;
      float bsv = bias[ncol];
#pragma unroll
      for (int m = 0; m < 4; ++m) {
#pragma unroll
        for (int r = 0; r < 4; ++r) {
          int row = m0 + wr*64 + m*16 + l4*4 + r;
          int b = row >> 11, s = row & 2047;
          base[(((size_t)b*NH_ + h)*S_ + s)*HD_ + d] = f2bf((acc[m][n][r] + bsv) * qsc);
        }
      }
    }
  }
}

// out-proj: C = ctx16 @ Wo + bo + residual(hs) -> fp32 xout
__global__ __launch_bounds__(256) void gemm_out_kernel(const u16* __restrict__ ctx16, const u16* __restrict__ wo,
                                                       const float* __restrict__ bo, const float* __restrict__ hs,
                                                       float* __restrict__ xout) {
  __shared__ __align__(16) u16 As[128*32], Bs[128*32];
  f32x4 acc[4][4] = {};
  const int lg = xcd_swz(blockIdx.x, 512);
  const int m0 = (lg / 8) * 128, n0 = (lg % 8) * 128;
  gemm_tile(ctx16, wo, m0, n0, As, Bs, acc);
  const int tid = threadIdx.x, lane = tid & 63, wave = tid >> 6;
  const int wr = wave >> 1, wc = wave & 1, l15 = lane & 15, l4 = lane >> 4;
#pragma unroll
  for (int n = 0; n < 4; ++n) {
    int col = n0 + wc*64 + n*16 + l15;
    float bsv = bo[col];
#pragma unroll
    for (int m = 0; m < 4; ++m) {
#pragma unroll
      for (int r = 0; r < 4; ++r) {
        int row = m0 + wr*64 + m*16 + l4*4 + r;
        size_t off = (size_t)row * H_ + col;
        xout[off] = acc[m][n][r] + bsv + hs[off];
      }
    }
  }
}

// ---------------- flash attention (4 waves x 64 q-rows = 2 strips, swapped QK^T) ----
// Each wave owns 64 q-rows as two 32-row strips: K/V fragment reads and staging are
// shared across strips (2x work per barrier / per LDS read), and the two strips'
// softmax dependency chains interleave (latency hiding). In-register softmax via
// swapped QK^T + cvt_pk/permlane32_swap; defer-max (T13); setprio (T5) on MFMA
// clusters; counted vmcnt(4) double-buffer staging via global_load_lds.

__device__ __forceinline__ void softmax_update(f32x16& s0, f32x16& s1, float& m_, float& l_,
                                               f32x16& O0, f32x16& O1, float* scrow,
                                               int l31, int hi) {
  float v[16];
#pragma unroll
  for (int r = 0; r < 16; ++r) v[r] = fmaxf(s0[r], s1[r]);
#pragma unroll
  for (int r = 0; r < 8; ++r) v[r] = fmaxf(v[r], v[r+8]);
#pragma unroll
  for (int r = 0; r < 4; ++r) v[r] = fmaxf(v[r], v[r+4]);
  float mx = fmaxf(fmaxf(v[0], v[1]), fmaxf(v[2], v[3]));
  { int a = __float_as_int(mx), b2 = a; plswap(a, b2);
    mx = fmaxf(__int_as_float(a), __int_as_float(b2)); }
  if (__any(mx > m_ + 8.f)) {
    float mnew = fmaxf(m_, mx);
    float sc = EXP2F(m_ - mnew);
    l_ *= sc; m_ = mnew;
    scrow[l31] = sc;
#pragma unroll
    for (int bq = 0; bq < 4; ++bq) {
      f32x4 scq = *(const f32x4*)&scrow[bq*8 + hi*4];
#pragma unroll
      for (int a = 0; a < 4; ++a) { O0[bq*4+a] *= scq[a]; O1[bq*4+a] *= scq[a]; }
    }
  }
#pragma unroll
  for (int r = 0; r < 16; ++r) s0[r] = EXP2F(s0[r] - m_);
#pragma unroll
  for (int r = 0; r < 16; ++r) s1[r] = EXP2F(s1[r] - m_);
#pragma unroll
  for (int r = 0; r < 16; ++r) v[r] = s0[r] + s1[r];
#pragma unroll
  for (int r = 0; r < 8; ++r) v[r] += v[r+8];
#pragma unroll
  for (int r = 0; r < 4; ++r) v[r] += v[r+4];
  float rs_ = (v[0] + v[1]) + (v[2] + v[3]);
  { int a = __float_as_int(rs_), b2 = a; plswap(a, b2);
    rs_ = __int_as_float(a) + __int_as_float(b2); }
  l_ += rs_;
}

__global__ __launch_bounds__(256, 2) void attn_kernel(const u16* __restrict__ q_, const u16* __restrict__ k_,
                                                      const u16* __restrict__ vt_, const float* __restrict__ madd_g,
                                                      const uint32_t* __restrict__ nzbits,
                                                      u16* __restrict__ ctx16) {
  __shared__ __align__(16) u16 Ks[2][64*64], Vs[2][64*64];
  __shared__ __align__(16) float Sc[4][64];
  const int lgid = xcd_swz(blockIdx.x, 512);
  const int qb = lgid & 7, bh = lgid >> 3, h = bh & 15, b = bh >> 4;
  const int tid = threadIdx.x, lane = tid & 63, wave = tid >> 6;
  const int l31 = lane & 31, hi = lane >> 5;
  const size_t headoff = ((size_t)b * NH_ + h) * ((size_t)S_ * HD_);
  const u16* Q  = q_ + headoff;
  const u16* K  = k_ + headoff;
  const u16* Vt = vt_ + headoff;     // [d][s]
  const uint32_t nzb = nzbits[b];
  const int qbase = qb*256 + wave*64;
  bf16x8 qfA[4], qfB[4];             // strip A rows qbase+l31, strip B rows qbase+32+l31
#pragma unroll
  for (int st = 0; st < 4; ++st) {
    qfA[st] = *(const bf16x8*)(Q + (size_t)(qbase + l31) * HD_ + st*16 + hi*8);
    qfB[st] = *(const bf16x8*)(Q + (size_t)(qbase + 32 + l31) * HD_ + st*16 + hi*8);
  }
  f32x16 O00 = {}, O01 = {}, O10 = {}, O11 = {};
  float mA = -3.0e38f, lA = 0.f, mB = -3.0e38f, lB = 0.f;
  const int srow = tid >> 3, sch = tid & 7;
  const int gch = sch ^ (srow & 7);           // inverse-XOR source chunk (involution)
  const int swzA = l31 & 7;                   // read-side row&7

#define STAGE(bb, kt) do { \
    const u16* Kt_ = K + (size_t)(kt) * 64 * HD_; \
    _Pragma("unroll") \
    for (int c = 0; c < 2; ++c) { \
      int row = c*32 + srow; \
      gload16(Kt_ + (size_t)row * HD_ + gch*8, &Ks[bb][c*2048 + (size_t)tid*8]); \
      gload16(Vt + (size_t)row * S_ + (kt)*64 + gch*8, &Vs[bb][c*2048 + (size_t)tid*8]); \
    } \
  } while (0)

  STAGE(0, 0);
  __syncthreads();   // prologue full drain: tile 0 staged

  for (int kt = 0; kt < 32; ++kt) {
    const int cur = kt & 1;
    const int nxt = (kt + 1) & 31;  // kt=31 stages a dummy (tile 0) to keep vmcnt uniform
    STAGE(cur ^ 1, nxt);
    asm volatile("s_waitcnt vmcnt(4)\n\ts_barrier" ::: "memory");
    // ---- QK^T: S^T[kv][q] for both strips; K frags shared ----
    f32x16 sA0 = {}, sA1 = {}, sB0 = {}, sB1 = {};
    __builtin_amdgcn_s_setprio(1);
#pragma unroll
    for (int st = 0; st < 4; ++st) {
      const int kch = ((2*st + hi) ^ swzA) * 8;
      bf16x8 kf0 = *(const bf16x8*)&Ks[cur][l31*64 + kch];
      bf16x8 kf1 = *(const bf16x8*)&Ks[cur][(32 + l31)*64 + kch];
      sA0 = mfma32(kf0, qfA[st], sA0);
      sA1 = mfma32(kf1, qfA[st], sA1);
      sB0 = mfma32(kf0, qfB[st], sB0);
      sB1 = mfma32(kf1, qfB[st], sB1);
    }
    __builtin_amdgcn_s_setprio(0);
    // ---- mask add (same madd for both strips), only when tile has masked cols ----
    if ((nzb >> kt) & 1u) {
#pragma unroll
      for (int t = 0; t < 2; ++t) {
        f32x16& sa = t ? sA1 : sA0;
        f32x16& sb = t ? sB1 : sB0;
#pragma unroll
        for (int bq = 0; bq < 4; ++bq) {
          f32x4 md = *(const f32x4*)(madd_g + (size_t)b * S_ + kt*64 + t*32 + bq*8 + hi*4);
#pragma unroll
          for (int a = 0; a < 4; ++a) { sa[bq*4 + a] += md[a]; sb[bq*4 + a] += md[a]; }
        }
      }
    }
    // ---- online softmax, two independent strips (chains interleave) ----
    softmax_update(sA0, sA1, mA, lA, O00, O01, &Sc[wave][0],  l31, hi);
    softmax_update(sB0, sB1, mB, lB, O10, O11, &Sc[wave][32], l31, hi);
    // ---- pack P -> bf16 frags (cvt_pk + permlane32_swap) and PV; V frags shared ----
    __builtin_amdgcn_s_setprio(1);
#pragma unroll
    for (int ks = 0; ks < 4; ++ks) {
      const f32x16& sa = (ks < 2) ? sA0 : sA1;
      const f32x16& sb = (ks < 2) ? sB0 : sB1;
      const int p = ks & 1;
      int pa0 = cvtpk(sa[8*p+0], sa[8*p+1]);
      int pa1 = cvtpk(sa[8*p+2], sa[8*p+3]);
      int pa2 = cvtpk(sa[8*p+4], sa[8*p+5]);
      int pa3 = cvtpk(sa[8*p+6], sa[8*p+7]);
      plswap(pa0, pa2); plswap(pa1, pa3);
      union { i32x4 i; bf16x8 hv; } ua; ua.i = (i32x4){pa0, pa1, pa2, pa3};
      int pb0 = cvtpk(sb[8*p+0], sb[8*p+1]);
      int pb1 = cvtpk(sb[8*p+2], sb[8*p+3]);
      int pb2 = cvtpk(sb[8*p+4], sb[8*p+5]);
      int pb3 = cvtpk(sb[8*p+6], sb[8*p+7]);
      plswap(pb0, pb2); plswap(pb1, pb3);
      union { i32x4 i; bf16x8 hv; } ub; ub.i = (i32x4){pb0, pb1, pb2, pb3};
      const int vch = ((2*ks + hi) ^ swzA) * 8;
      bf16x8 vb0 = *(const bf16x8*)&Vs[cur][l31*64 + vch];
      bf16x8 vb1 = *(const bf16x8*)&Vs[cur][(32 + l31)*64 + vch];
      O00 = mfma32(ua.hv, vb0, O00);
      O01 = mfma32(ua.hv, vb1, O01);
      O10 = mfma32(ub.hv, vb0, O10);
      O11 = mfma32(ub.hv, vb1, O11);
    }
    __builtin_amdgcn_s_setprio(0);
    asm volatile("s_barrier" ::: "memory");  // all waves done reading buf[cur]
  }
  asm volatile("s_waitcnt vmcnt(0)" ::: "memory");  // drain dummy stage before LDS dealloc
  // ---- epilogue: normalize (1/l broadcast to crow layout) and write ctx ----
  Sc[wave][l31]      = 1.0f / lA;
  Sc[wave][32 + l31] = 1.0f / lB;
#pragma unroll
  for (int bq = 0; bq < 4; ++bq) {
    f32x4 i0 = *(const f32x4*)&Sc[wave][bq*8 + hi*4];
    f32x4 i1 = *(const f32x4*)&Sc[wave][32 + bq*8 + hi*4];
#pragma unroll
    for (int a = 0; a < 4; ++a) {
      int ql = 8*bq + 4*hi + a, r = bq*4 + a;   // q_local = (r&3) + 8*(r>>2) + 4*hi
      int sA_ = qbase + ql;
      size_t ob0 = ((size_t)(b * S_ + sA_) * NH_ + h) * HD_;
      ctx16[ob0 + l31]      = f2bf(O00[r] * i0[a]);
      ctx16[ob0 + 32 + l31] = f2bf(O01[r] * i0[a]);
      int sB_ = qbase + 32 + ql;
      size_t ob1 = ((size_t)(b * S_ + sB_) * NH_ + h) * HD_;
      ctx16[ob1 + l31]      = f2bf(O10[r] * i1[a]);
      ctx16[ob1 + 32 + l31] = f2bf(O11[r] * i1[a]);
    }
  }
#undef STAGE
}

// ---------------- LayerNorm (in-place on d_out) ----------------

__global__ __launch_bounds__(256) void ln_kernel(float* __restrict__ x, const float* __restrict__ g,
                                                 const float* __restrict__ bb) {
  const int row = blockIdx.x, t = threadIdx.x;
  float* xr = x + (size_t)row * H_;
  f32x4 v = ((const f32x4*)xr)[t];
  float s = v.x + v.y + v.z + v.w;
  float s2 = v.x*v.x + v.y*v.y + v.z*v.z + v.w*v.w;
#pragma unroll
  for (int o = 1; o < 64; o <<= 1) { s += __shfl_xor(s, o, 64); s2 += __shfl_xor(s2, o, 64); }
  __shared__ float red[8];
  const int wave = t >> 6, lane = t & 63;
  if (lane == 0) { red[wave] = s; red[4 + wave] = s2; }
  __syncthreads();
  s = red[0] + red[1] + red[2] + red[3];
  s2 = red[4] + red[5] + red[6] + red[7];
  const float mu = s * (1.0f / H_);
  const float var = s2 * (1.0f / H_) - mu * mu;
  const float rs = rsqrtf(var + 1e-12f);
  f32x4 gg = ((const f32x4*)g)[t], bb4 = ((const f32x4*)bb)[t];
  f32x4 o;
  o.x = (v.x - mu) * rs * gg.x + bb4.x;
  o.y = (v.y - mu) * rs * gg.y + bb4.y;
  o.z = (v.z - mu) * rs * gg.z + bb4.z;
  o.w = (v.w - mu) * rs * gg.w + bb4.w;
  ((f32x4*)xr)[t] = o;
}

// ---------------- launch ----------------

extern "C" void kernel_launch(void* const* d_in, const int* in_sizes, int n_in,
                              void* d_out, int out_size, void* d_ws, size_t ws_size,
                              hipStream_t stream) {
  (void)in_sizes; (void)n_in; (void)out_size; (void)ws_size;
  const float* hs   = (const float*)d_in[0];
  const float* mask = (const float*)d_in[1];
  const float* Wq = (const float*)d_in[2];
  const float* bq = (const float*)d_in[3];
  const float* Wk = (const float*)d_in[4];
  const float* bk = (const float*)d_in[5];
  const float* Wv = (const float*)d_in[6];
  const float* bv = (const float*)d_in[7];
  const float* Wo = (const float*)d_in[8];
  const float* bo = (const float*)d_in[9];
  const float* lg = (const float*)d_in[10];
  const float* lb = (const float*)d_in[11];
  float* out = (float*)d_out;

  uint8_t* w = (uint8_t*)d_ws;
  u16* hs16  = (u16*)w;                                 // 16 MB: (M,H) bf16
  u16* wt16  = (u16*)(w + ((size_t)16 << 20));          //  8 MB: 4x (N,K) bf16 W^T
  u16* qkv16 = (u16*)(w + ((size_t)24 << 20));          // 48 MB: Q,K [b][h][s][d]; V [b][h][d][s]
  u16* ctx16 = (u16*)(w + ((size_t)72 << 20));          // 16 MB: (M,H) bf16
  float* madd_g = (float*)(w + ((size_t)88 << 20));     // 32 KB: (B,S) mask add
  uint32_t* nzbits = (uint32_t*)(w + ((size_t)88 << 20) + 32768);  // 16 B

  const size_t psz = (size_t)B_*NH_*S_*HD_;
  cvt_hs_kernel<<<dim3(M_*H_/(256*8) + 4), dim3(256), 0, stream>>>(hs, hs16, mask, madd_g, nzbits);
  cvt_wT_kernel<<<dim3(16, 16, 4), dim3(256), 0, stream>>>(Wq, Wk, Wv, Wo, wt16);
  gemm_qkv_kernel<<<dim3(1536), dim3(256), 0, stream>>>(hs16, wt16, bq, bk, bv, qkv16);
  attn_kernel<<<dim3(512), dim3(256), 0, stream>>>(qkv16, qkv16 + psz, qkv16 + 2*psz, madd_g, nzbits, ctx16);
  gemm_out_kernel<<<dim3(512), dim3(256), 0, stream>>>(ctx16, wt16 + (size_t)3*H_*H_, bo, hs, out);
  ln_kernel<<<dim3(M_), dim3(256), 0, stream>>>(out, lg, lb);
}